// Round 8
// baseline (1076.646 us; speedup 1.0000x reference)
//
#include <hip/hip_runtime.h>

#define B_  16
#define S_  128
#define N_  13
#define D_  128
#define E_  6
#define M_  64
#define H_  4
#define HD_ 16

// fp32 LDS row paddings (floats), 16B-aligned rows
#define DP  (D_ + 4)       // ns rows: 132
#define QP  (3 * M_ + 4)   // qkv rows: 196
// bf16 LDS row strides (halfwords), 16B-aligned rows
#define MPH 72             // 64 ch + pad (144 B)
#define NPH 136            // 128 ch + pad (272 B)

// compiler-only ordering for same-wave LDS park->read (DS pipe is in-order per wave)
#define LDS_ORDER() __asm__ __volatile__("" ::: "memory")

typedef float v2f __attribute__((ext_vector_type(2)));
typedef float v4f __attribute__((ext_vector_type(4)));
typedef unsigned int v4u __attribute__((ext_vector_type(4)));

#if __has_builtin(__builtin_elementwise_fma)
#define PKFMA(A, B, C) __builtin_elementwise_fma((A), (B), (C))
#else
#define PKFMA(A, B, C) ((A) * (B) + (C))
#endif
#define LO2(X) __builtin_shufflevector((X), (X), 0, 1)
#define HI2(X) __builtin_shufflevector((X), (X), 2, 3)

__device__ __forceinline__ v2f mkpair(float a, float b) { v2f r; r.x = a; r.y = b; return r; }
__device__ __forceinline__ float hsum2(v2f v) { return v.x + v.y; }

// bf16 pack (RTNE) / unpack-pair (2 VALU per pair)
__device__ __forceinline__ unsigned short f2bs(float x) {
    unsigned u = __float_as_uint(x);
    u += 0x7FFFu + ((u >> 16) & 1u);
    return (unsigned short)(u >> 16);
}
#define BPAIR(U) mkpair(__uint_as_float((U) << 16), __uint_as_float((U) & 0xFFFF0000u))

// A&S 7.1.26 erf approximation, |eps| < 1.5e-7
__device__ __forceinline__ float erf_fast(float x) {
    float ax = fabsf(x);
    float t  = __builtin_amdgcn_rcpf(fmaf(0.3275911f, ax, 1.0f));
    float p  = t * fmaf(t, fmaf(t, fmaf(t, fmaf(t, 1.061405429f, -1.453152027f),
                                        1.421413741f), -0.284496736f), 0.254829592f);
    float r  = fmaf(-p, __expf(-ax * ax), 1.0f);
    return copysignf(r, x);
}
__device__ __forceinline__ float geluf(float x) {
    return 0.5f * x * (1.0f + erf_fast(x * 0.7071067811865475f));
}
__device__ __forceinline__ float sigm(float x) { return 1.0f / (1.0f + __expf(-x)); }
__device__ __forceinline__ float wsum64(float v) {
#pragma unroll
    for (int o = 32; o; o >>= 1) v += __shfl_xor(v, o, 64);
    return v;
}
__device__ __forceinline__ void wsum4s(float &a, float &b, float &c, float &d) {
#pragma unroll
    for (int o = 32; o; o >>= 1) {
        float ta = __shfl_xor(a, o, 64);
        float tb = __shfl_xor(b, o, 64);
        float tc = __shfl_xor(c, o, 64);
        float td = __shfl_xor(d, o, 64);
        a += ta; b += tb; c += tc; d += td;
    }
}
__device__ __forceinline__ void wsum8s(float &a0, float &a1, float &a2, float &a3,
                                       float &a4, float &a5, float &a6, float &a7) {
#pragma unroll
    for (int o = 32; o; o >>= 1) {
        float t0 = __shfl_xor(a0, o, 64), t1 = __shfl_xor(a1, o, 64);
        float t2 = __shfl_xor(a2, o, 64), t3 = __shfl_xor(a3, o, 64);
        float t4 = __shfl_xor(a4, o, 64), t5 = __shfl_xor(a5, o, 64);
        float t6 = __shfl_xor(a6, o, 64), t7 = __shfl_xor(a7, o, 64);
        a0 += t0; a1 += t1; a2 += t2; a3 += t3;
        a4 += t4; a5 += t5; a6 += t6; a7 += t7;
    }
}
// single-pass LN over 64 lanes for 4 independent edges: var = E[x^2] - mean^2
template <bool DOGELU>
__device__ __forceinline__ void ln4q(float &a, float &b, float &c, float &d,
                                     float lg, float lb) {
    float sa = a, sb = b, sc = c, sd = d;
    float qa = a * a, qb = b * b, qc = c * c, qd = d * d;
    wsum8s(sa, sb, sc, sd, qa, qb, qc, qd);
    float ma = sa * (1.f / 64.f), mb = sb * (1.f / 64.f);
    float mc = sc * (1.f / 64.f), md = sd * (1.f / 64.f);
    float va = fmaxf(qa * (1.f / 64.f) - ma * ma, 0.f);
    float vb = fmaxf(qb * (1.f / 64.f) - mb * mb, 0.f);
    float vc = fmaxf(qc * (1.f / 64.f) - mc * mc, 0.f);
    float vd = fmaxf(qd * (1.f / 64.f) - md * md, 0.f);
    a = (a - ma) * rsqrtf(va + 1e-5f) * lg + lb;
    b = (b - mb) * rsqrtf(vb + 1e-5f) * lg + lb;
    c = (c - mc) * rsqrtf(vc + 1e-5f) * lg + lb;
    d = (d - md) * rsqrtf(vd + 1e-5f) * lg + lb;
    if (DOGELU) { a = geluf(a); b = geluf(b); c = geluf(c); d = geluf(d); }
}

// workspace layout (float offsets). packed[(k4*O + ch)*4 + kk] = W[(4k4+kk)*O + ch]
#define OFF_WTS   0        // 64x64 folded  ee_w2@ts_w1, packed
#define OFF_WMC   4096     // 64x64 folded  ee_w2@mc_w1[128:134], packed
#define OFF_BTS   8192     // 64 folded bias for TS1
#define OFF_BMC   8256     // 64 folded bias for MC1
#define OFF_MC1P  8320     // mc_w1[0:128] packed (K=128,O=64)
#define OFF_MC2P  16512    // mc_w2 packed (64,64)
#define OFF_ATP   20608    // at_in_w packed (64,192)
#define OFF_TS2P  32896    // ts_w2 packed (64,32)
#define OFF_AOP   34944    // at_out_w packed (64,64)
#define OFF_AG1P  39040    // ag_w1 packed (64,128)
#define OFF_AG2P  47232    // ag_w2 packed (128,128)
#define OFF_GTP   63616    // gt_w packed (256,128)
#define WS_TOTAL  96384    // 385,536 bytes

struct Params {
    const float *node_states, *edge_features;
    const float *ee_w1, *ee_b1, *ee_ln_g, *ee_ln_b, *ee_w2, *ee_b2;
    const float *ts_w1, *ts_b1, *ts_ln_g, *ts_ln_b, *ts_w2, *ts_b2, *ts_w3, *ts_b3;
    const float *mc_w1, *mc_b1, *mc_ln_g, *mc_ln_b, *mc_w2, *mc_b2;
    const float *at_in_w, *at_in_b, *at_out_w, *at_out_b;
    const float *ag_w1, *ag_b1, *ag_ln_g, *ag_ln_b, *ag_w2, *ag_b2;
    const float *gt_w, *gt_b, *nn_ln_g, *nn_ln_b, *mn_ln_g, *mn_ln_b;
    float *ws;   // d_ws
    float *out;
};

// ---- prep: fold enc-matrices + pack weights k4-contiguous into d_ws ----
__global__ __launch_bounds__(256) void prep_kernel(Params p) {
    int i = blockIdx.x * 256 + threadIdx.x;
    if (i >= WS_TOTAL) return;
    float v;
    if (i < OFF_WMC) {                       // W_ts = ee_w2 @ ts_w1, packed
        int r = i >> 2, kk = i & 3;
        int k4 = r >> 6, o = r & 63, m = 4 * k4 + kk;
        float s = 0.f;
        for (int e = 0; e < E_; e++) s += p.ee_w2[m * E_ + e] * p.ts_w1[e * M_ + o];
        v = s;
    } else if (i < OFF_BTS) {                // W_mce = ee_w2 @ mc_w1[128:134], packed
        int j = i - OFF_WMC;
        int r = j >> 2, kk = j & 3;
        int k4 = r >> 6, o = r & 63, m = 4 * k4 + kk;
        float s = 0.f;
        for (int e = 0; e < E_; e++) s += p.ee_w2[m * E_ + e] * p.mc_w1[(D_ + e) * M_ + o];
        v = s;
    } else if (i < OFF_BMC) {                // folded TS1 bias
        int o = i - OFF_BTS;
        float s = p.ts_b1[o];
        for (int e = 0; e < E_; e++) s += p.ee_b2[e] * p.ts_w1[e * M_ + o];
        v = s;
    } else if (i < OFF_MC1P) {               // folded MC1 bias
        int o = i - OFF_BMC;
        float s = p.mc_b1[o];
        for (int e = 0; e < E_; e++) s += p.ee_b2[e] * p.mc_w1[(D_ + e) * M_ + o];
        v = s;
    } else if (i < OFF_MC2P) {               // mc_w1 src-part packed
        int j = i - OFF_MC1P; int r = j >> 2, kk = j & 3;
        int k4 = r >> 6, ch = r & 63;
        v = p.mc_w1[(4 * k4 + kk) * M_ + ch];
    } else if (i < OFF_ATP) {                // mc_w2 packed
        int j = i - OFF_MC2P; int r = j >> 2, kk = j & 3;
        int k4 = r >> 6, ch = r & 63;
        v = p.mc_w2[(4 * k4 + kk) * M_ + ch];
    } else if (i < OFF_TS2P) {               // at_in_w packed
        int j = i - OFF_ATP; int r = j >> 2, kk = j & 3;
        int k4 = r / 192, ch = r % 192;
        v = p.at_in_w[(4 * k4 + kk) * 192 + ch];
    } else if (i < OFF_AOP) {                // ts_w2 packed
        int j = i - OFF_TS2P; int r = j >> 2, kk = j & 3;
        int k4 = r >> 5, ch = r & 31;
        v = p.ts_w2[(4 * k4 + kk) * 32 + ch];
    } else if (i < OFF_AG1P) {               // at_out_w packed
        int j = i - OFF_AOP; int r = j >> 2, kk = j & 3;
        int k4 = r >> 6, ch = r & 63;
        v = p.at_out_w[(4 * k4 + kk) * M_ + ch];
    } else if (i < OFF_AG2P) {               // ag_w1 packed
        int j = i - OFF_AG1P; int r = j >> 2, kk = j & 3;
        int k4 = r >> 7, ch = r & 127;
        v = p.ag_w1[(4 * k4 + kk) * D_ + ch];
    } else if (i < OFF_GTP) {                // ag_w2 packed
        int j = i - OFF_AG2P; int r = j >> 2, kk = j & 3;
        int k4 = r >> 7, ch = r & 127;
        v = p.ag_w2[(4 * k4 + kk) * D_ + ch];
    } else {                                 // gt_w packed
        int j = i - OFF_GTP; int r = j >> 2, kk = j & 3;
        int k4 = r >> 7, ch = r & 127;
        v = p.gt_w[(4 * k4 + kk) * D_ + ch];
    }
    p.ws[i] = v;
}

// unpack 4 edges' 8 bf16 k-values into named pairs (2 VALU per pair)
#define UNPACK_X()                                                                     \
    v2f x0a = BPAIR(u0.x), x0b = BPAIR(u0.y), x0c = BPAIR(u0.z), x0d = BPAIR(u0.w);    \
    v2f x1a = BPAIR(u1.x), x1b = BPAIR(u1.y), x1c = BPAIR(u1.z), x1d = BPAIR(u1.w);    \
    v2f x2a = BPAIR(u2.x), x2b = BPAIR(u2.y), x2c = BPAIR(u2.z), x2d = BPAIR(u2.w);    \
    v2f x3a = BPAIR(u3.x), x3b = BPAIR(u3.y), x3c = BPAIR(u3.z), x3d = BPAIR(u3.w);

#define BDOT4(P0, P1, P2, P3, WA, WB)                                                  \
    { v2f a01 = LO2(WA), a23 = HI2(WA), b01 = LO2(WB), b23 = HI2(WB);                  \
      P0 = PKFMA(x0a, a01, PKFMA(x0b, a23, PKFMA(x0c, b01, PKFMA(x0d, b23, P0))));     \
      P1 = PKFMA(x1a, a01, PKFMA(x1b, a23, PKFMA(x1c, b01, PKFMA(x1d, b23, P1))));     \
      P2 = PKFMA(x2a, a01, PKFMA(x2b, a23, PKFMA(x2c, b01, PKFMA(x2d, b23, P2))));     \
      P3 = PKFMA(x3a, a01, PKFMA(x3b, a23, PKFMA(x3c, b01, PKFMA(x3d, b23, P3)))); }

// one block per (b,s,target). 4 waves; wave w owns edges {w, w+4, w+8, (w==0: 12)}.
// Inter-stage activations parked in LDS as bf16 (halves DS b128 broadcast traffic —
// the measured bottleneck). enc folded away via precomputed W_ts/W_mce.
__global__ __launch_bounds__(256, 4) void petri_kernel(Params p) {
    const int tid  = threadIdx.x;
    const int wave = tid >> 6;
    const int lane = tid & 63;
    const int blk  = blockIdx.x;
    const int bs   = blk / N_;
    const int t    = blk - bs * N_;

    const int  j0 = wave, j1 = wave + 4, j2 = wave + 8;
    const bool act3 = (wave == 0);
    const int  j3 = act3 ? 12 : 0;

    __shared__ __align__(16) float ns[N_][DP];            // fp32 node states
    __shared__ __align__(16) unsigned short nsb[N_][NPH]; // bf16 node states
    __shared__ __align__(16) unsigned short hb[N_][MPH];  // bf16 h (E1 out)
    __shared__ __align__(16) unsigned short xb[N_][MPH];  // bf16 parking: t1 -> mh -> wm
    __shared__ __align__(16) float qkv[N_][QP];
    __shared__ __align__(16) float sc[H_][N_][N_];
    __shared__ __align__(16) float wsm[H_][16];
    __shared__ __align__(16) float aggp[M_];
    __shared__ __align__(16) float agg2[M_];
    __shared__ __align__(16) float a1l[D_];
    __shared__ __align__(16) float nil[D_];
    __shared__ __align__(16) float gzp[2][D_];
    __shared__ float red[4];

    const float *ws = p.ws;

    // ---- stage node states -> LDS (fp32 + bf16 copy) ----
    {
        const v4f *g4 = (const v4f *)(p.node_states + (size_t)bs * N_ * D_);
        for (int i = tid; i < N_ * (D_ / 4); i += 256) {
            int row = i >> 5, c4 = i & 31;           // D_/4 == 32
            v4f x = g4[i];
            ((v4f *)&ns[row][0])[c4] = x;
            unsigned short h0 = f2bs(x.x), h1 = f2bs(x.y), h2 = f2bs(x.z), h3 = f2bs(x.w);
            unsigned lohw = (unsigned)h0 | ((unsigned)h1 << 16);
            unsigned hihw = (unsigned)h2 | ((unsigned)h3 << 16);
            unsigned *dst = (unsigned *)&nsb[row][4 * c4];
            dst[0] = lohw; dst[1] = hihw;
        }
    }
    __syncthreads();

    // =======================  edge phase  =======================
    float acc0, acc1, acc2, acc3;

    // ---- E1: ef @ ee_w1 -> LN -> gelu -> park h (bf16) ----
    {
        const float *efb = p.edge_features + ((size_t)bs * N_ * N_ + t) * E_;
        const v2f *e0p = (const v2f *)(efb + j0 * (N_ * E_));
        const v2f *e1p = (const v2f *)(efb + j1 * (N_ * E_));
        const v2f *e2p = (const v2f *)(efb + j2 * (N_ * E_));
        const v2f *e3p = (const v2f *)(efb + j3 * (N_ * E_));
        float bb = p.ee_b1[lane];
        v2f p0 = {bb, 0.f}, p1 = {bb, 0.f}, p2 = {bb, 0.f}, p3 = {bb, 0.f};
#pragma unroll
        for (int e2 = 0; e2 < 3; e2++) {
            v2f w01 = mkpair(p.ee_w1[(2 * e2) * M_ + lane], p.ee_w1[(2 * e2 + 1) * M_ + lane]);
            p0 = PKFMA(e0p[e2], w01, p0);
            p1 = PKFMA(e1p[e2], w01, p1);
            p2 = PKFMA(e2p[e2], w01, p2);
            p3 = PKFMA(e3p[e2], w01, p3);
        }
        acc0 = hsum2(p0); acc1 = hsum2(p1); acc2 = hsum2(p2); acc3 = hsum2(p3);
        ln4q<true>(acc0, acc1, acc2, acc3, p.ee_ln_g[lane], p.ee_ln_b[lane]);
        hb[j0][lane] = f2bs(acc0);
        hb[j1][lane] = f2bs(acc1);
        hb[j2][lane] = f2bs(acc2);
        if (act3) hb[j3][lane] = f2bs(acc3);
        LDS_ORDER();
    }

    // ---- TS1 (folded): t1 = h @ W_ts + b_ts -> LN -> gelu -> park t1 ----
    float ts0, ts1, ts2, ts3;
    {
        const v4f *wt = (const v4f *)(ws + OFF_WTS);
        float bb = ws[OFF_BTS + lane];
        v2f p0 = {bb, 0.f}, p1 = {bb, 0.f}, p2 = {bb, 0.f}, p3 = {bb, 0.f};
#pragma unroll 2
        for (int k8 = 0; k8 < 8; k8++) {
            v4u u0 = *(const v4u *)&hb[j0][8 * k8];
            v4u u1 = *(const v4u *)&hb[j1][8 * k8];
            v4u u2 = *(const v4u *)&hb[j2][8 * k8];
            v4u u3 = *(const v4u *)&hb[j3][8 * k8];
            UNPACK_X()
            v4f wA = wt[(2 * k8) * M_ + lane];
            v4f wB = wt[(2 * k8 + 1) * M_ + lane];
            BDOT4(p0, p1, p2, p3, wA, wB)
        }
        float t10 = hsum2(p0), t11 = hsum2(p1), t12 = hsum2(p2), t13 = hsum2(p3);
        ln4q<true>(t10, t11, t12, t13, p.ts_ln_g[lane], p.ts_ln_b[lane]);
        xb[j0][lane] = f2bs(t10);
        xb[j1][lane] = f2bs(t11);
        xb[j2][lane] = f2bs(t12);
        if (act3) xb[j3][lane] = f2bs(t13);
        LDS_ORDER();

        // ---- TS2/TS3: M -> 32 -> 1, sigmoid ----
        const int l31 = lane & 31;
        const v4f *tp = (const v4f *)(ws + OFF_TS2P);
        float b2v = p.ts_b2[l31];
        v2f q0 = {b2v, 0.f}, q1 = {b2v, 0.f}, q2 = {b2v, 0.f}, q3 = {b2v, 0.f};
#pragma unroll 2
        for (int k8 = 0; k8 < 8; k8++) {
            v4u u0 = *(const v4u *)&xb[j0][8 * k8];
            v4u u1 = *(const v4u *)&xb[j1][8 * k8];
            v4u u2 = *(const v4u *)&xb[j2][8 * k8];
            v4u u3 = *(const v4u *)&xb[j3][8 * k8];
            UNPACK_X()
            v4f wA = tp[(2 * k8) * 32 + l31];
            v4f wB = tp[(2 * k8 + 1) * 32 + l31];
            BDOT4(q0, q1, q2, q3, wA, wB)
        }
        float t20 = hsum2(q0), t21 = hsum2(q1), t22 = hsum2(q2), t23 = hsum2(q3);
        float w3v = p.ts_w3[l31], b3v = p.ts_b3[0];
        float r0 = geluf(t20) * w3v, r1 = geluf(t21) * w3v;
        float r2 = geluf(t22) * w3v, r3 = geluf(t23) * w3v;
        wsum4s(r0, r1, r2, r3);  // 32-halves duplicated -> x0.5
        ts0 = sigm(r0 * 0.5f + b3v);
        ts1 = sigm(r1 * 0.5f + b3v);
        ts2 = sigm(r2 * 0.5f + b3v);
        ts3 = sigm(r3 * 0.5f + b3v);
    }

    // ---- MC1: ns @ mc_w1[0:128] + h @ W_mce + b_mc -> LN -> gelu -> park mh ----
    {
        const v4f *m1p = (const v4f *)(ws + OFF_MC1P);
        const v4f *wm  = (const v4f *)(ws + OFF_WMC);
        float bb = ws[OFF_BMC + lane];
        v2f p0 = {bb, 0.f}, p1 = {bb, 0.f}, p2 = {bb, 0.f}, p3 = {bb, 0.f};
#pragma unroll 2
        for (int k8 = 0; k8 < 16; k8++) {        // src-state part, K=128 bf16
            v4u u0 = *(const v4u *)&nsb[j0][8 * k8];
            v4u u1 = *(const v4u *)&nsb[j1][8 * k8];
            v4u u2 = *(const v4u *)&nsb[j2][8 * k8];
            v4u u3 = *(const v4u *)&nsb[j3][8 * k8];
            UNPACK_X()
            v4f wA = m1p[(2 * k8) * M_ + lane];
            v4f wB = m1p[(2 * k8 + 1) * M_ + lane];
            BDOT4(p0, p1, p2, p3, wA, wB)
        }
#pragma unroll 2
        for (int k8 = 0; k8 < 8; k8++) {         // folded enc part via h, K=64
            v4u u0 = *(const v4u *)&hb[j0][8 * k8];
            v4u u1 = *(const v4u *)&hb[j1][8 * k8];
            v4u u2 = *(const v4u *)&hb[j2][8 * k8];
            v4u u3 = *(const v4u *)&hb[j3][8 * k8];
            UNPACK_X()
            v4f wA = wm[(2 * k8) * M_ + lane];
            v4f wB = wm[(2 * k8 + 1) * M_ + lane];
            BDOT4(p0, p1, p2, p3, wA, wB)
        }
        acc0 = hsum2(p0); acc1 = hsum2(p1); acc2 = hsum2(p2); acc3 = hsum2(p3);
        ln4q<true>(acc0, acc1, acc2, acc3, p.mc_ln_g[lane], p.mc_ln_b[lane]);
        xb[j0][lane] = f2bs(acc0);
        xb[j1][lane] = f2bs(acc1);
        xb[j2][lane] = f2bs(acc2);
        if (act3) xb[j3][lane] = f2bs(acc3);     // mh (t1 consumed)
        LDS_ORDER();
    }

    // ---- MC2: mh @ mc_w2 ; wm = LN(msg*ts) -> park wm ----
    {
        const v4f *m2p = (const v4f *)(ws + OFF_MC2P);
        float bb = p.mc_b2[lane];
        v2f p0 = {bb, 0.f}, p1 = {bb, 0.f}, p2 = {bb, 0.f}, p3 = {bb, 0.f};
#pragma unroll 2
        for (int k8 = 0; k8 < 8; k8++) {
            v4u u0 = *(const v4u *)&xb[j0][8 * k8];
            v4u u1 = *(const v4u *)&xb[j1][8 * k8];
            v4u u2 = *(const v4u *)&xb[j2][8 * k8];
            v4u u3 = *(const v4u *)&xb[j3][8 * k8];
            UNPACK_X()
            v4f wA = m2p[(2 * k8) * M_ + lane];
            v4f wB = m2p[(2 * k8 + 1) * M_ + lane];
            BDOT4(p0, p1, p2, p3, wA, wB)
        }
        float m0 = hsum2(p0), m1 = hsum2(p1), m2 = hsum2(p2), m3 = hsum2(p3);
        m0 *= ts0; m1 *= ts1; m2 *= ts2; m3 *= ts3;
        ln4q<false>(m0, m1, m2, m3, p.mn_ln_g[lane], p.mn_ln_b[lane]);
        xb[j0][lane] = f2bs(m0);
        xb[j1][lane] = f2bs(m1);
        xb[j2][lane] = f2bs(m2);
        if (act3) xb[j3][lane] = f2bs(m3);       // wm (mh consumed)
        LDS_ORDER();
    }

    // ---- AT: qkv = wm @ at_in_w + b (fp32 out) ----
    {
        const v4f *atp = (const v4f *)(ws + OFF_ATP);
        float qb = p.at_in_b[lane];
        float kb = p.at_in_b[M_ + lane];
        float vb = p.at_in_b[2 * M_ + lane];
        v2f qp0 = {qb, 0.f}, qp1 = {qb, 0.f}, qp2 = {qb, 0.f}, qp3 = {qb, 0.f};
        v2f kp0 = {kb, 0.f}, kp1 = {kb, 0.f}, kp2 = {kb, 0.f}, kp3 = {kb, 0.f};
        v2f vp0 = {vb, 0.f}, vp1 = {vb, 0.f}, vp2 = {vb, 0.f}, vp3 = {vb, 0.f};
#pragma unroll 2
        for (int k8 = 0; k8 < 8; k8++) {
            v4u u0 = *(const v4u *)&xb[j0][8 * k8];
            v4u u1 = *(const v4u *)&xb[j1][8 * k8];
            v4u u2 = *(const v4u *)&xb[j2][8 * k8];
            v4u u3 = *(const v4u *)&xb[j3][8 * k8];
            UNPACK_X()
            {
                v4f wA = atp[(2 * k8) * 192 + lane];
                v4f wB = atp[(2 * k8 + 1) * 192 + lane];
                BDOT4(qp0, qp1, qp2, qp3, wA, wB)
            }
            {
                v4f wA = atp[(2 * k8) * 192 + 64 + lane];
                v4f wB = atp[(2 * k8 + 1) * 192 + 64 + lane];
                BDOT4(kp0, kp1, kp2, kp3, wA, wB)
            }
            {
                v4f wA = atp[(2 * k8) * 192 + 128 + lane];
                v4f wB = atp[(2 * k8 + 1) * 192 + 128 + lane];
                BDOT4(vp0, vp1, vp2, vp3, wA, wB)
            }
        }
        qkv[j0][lane] = hsum2(qp0); qkv[j0][M_ + lane] = hsum2(kp0); qkv[j0][2 * M_ + lane] = hsum2(vp0);
        qkv[j1][lane] = hsum2(qp1); qkv[j1][M_ + lane] = hsum2(kp1); qkv[j1][2 * M_ + lane] = hsum2(vp1);
        qkv[j2][lane] = hsum2(qp2); qkv[j2][M_ + lane] = hsum2(kp2); qkv[j2][2 * M_ + lane] = hsum2(vp2);
        if (act3) {
            qkv[j3][lane] = hsum2(qp3); qkv[j3][M_ + lane] = hsum2(kp3); qkv[j3][2 * M_ + lane] = hsum2(vp3);
        }
    }
    __syncthreads();

    // =======================  attention phase  =======================
    for (int pidx = tid; pidx < H_ * N_ * N_; pidx += 256) {
        int hh = pidx / (N_ * N_), r = pidx % (N_ * N_);
        int q = r / N_, k = r % N_;
        const v4f *qr = (const v4f *)&qkv[q][hh * HD_];
        const v4f *kr = (const v4f *)&qkv[k][M_ + hh * HD_];
        v2f sp = {0.f, 0.f};
#pragma unroll
        for (int d = 0; d < HD_ / 4; d++) {
            v4f a = qr[d], b = kr[d];
            sp = PKFMA(LO2(a), LO2(b), PKFMA(HI2(a), HI2(b), sp));
        }
        sc[hh][q][k] = hsum2(sp) * 0.25f;  // 1/sqrt(16)
    }
    __syncthreads();
    if (tid < H_ * N_) {  // softmax rows
        int hh = tid / N_, q = tid % N_;
        float mx = -1e30f;
        for (int k = 0; k < N_; k++) mx = fmaxf(mx, sc[hh][q][k]);
        float se = 0.f;
        for (int k = 0; k < N_; k++) {
            float e = __expf(sc[hh][q][k] - mx);
            se += e; sc[hh][q][k] = e;
        }
        float inv = 1.f / se;
        for (int k = 0; k < N_; k++) sc[hh][q][k] *= inv;
    }
    __syncthreads();
    if (tid < H_ * N_) {  // column sums over q (mean-over-q is linear)
        int hh = tid / N_, k = tid % N_;
        float s = 0.f;
        for (int q = 0; q < N_; q++) s += sc[hh][q][k];
        wsm[hh][k] = s;
    }
    __syncthreads();
    if (tid < M_) {  // agg_pre = (1/13) * (colsum @ v)
        int hh  = tid >> 4;
        float s = 0.f;
        for (int k = 0; k < N_; k++) s += wsm[hh][k] * qkv[k][2 * M_ + tid];
        aggp[tid] = s * (1.0f / 13.0f);
    }
    __syncthreads();
    if (tid < M_) {  // at_out (after mean, by linearity), packed weights
        const v4f *aop = (const v4f *)(ws + OFF_AOP);
        v2f sp = {p.at_out_b[tid], 0.f};
#pragma unroll 4
        for (int k4 = 0; k4 < 16; k4++) {
            v4f x = *(const v4f *)&aggp[4 * k4];
            v4f w = aop[k4 * M_ + tid];
            sp = PKFMA(LO2(x), LO2(w), PKFMA(HI2(x), HI2(w), sp));
        }
        agg2[tid] = hsum2(sp);
    }
    __syncthreads();

    // =======================  node update phase  =======================
    float a1 = 0.f;
    if (tid < D_) {
        const v4f *agp = (const v4f *)(ws + OFF_AG1P);
        v2f sp = {p.ag_b1[tid], 0.f};
#pragma unroll 4
        for (int k4 = 0; k4 < 16; k4++) {
            v4f x = *(const v4f *)&agg2[4 * k4];
            v4f w = agp[k4 * D_ + tid];
            sp = PKFMA(LO2(x), LO2(w), PKFMA(HI2(x), HI2(w), sp));
        }
        a1 = hsum2(sp);
    }
    {   // LN over 128 (threads 0..127 = waves 0,1)
        float s = wsum64(tid < D_ ? a1 : 0.f);
        if (lane == 0) red[wave] = s;
        __syncthreads();
        float mean = (red[0] + red[1]) * (1.f / 128.f);
        __syncthreads();
        float d  = a1 - mean;
        float s2 = wsum64(tid < D_ ? d * d : 0.f);
        if (lane == 0) red[wave] = s2;
        __syncthreads();
        float var = (red[0] + red[1]) * (1.f / 128.f);
        __syncthreads();
        if (tid < D_)
            a1 = geluf(d * rsqrtf(var + 1e-5f) * p.ag_ln_g[tid] + p.ag_ln_b[tid]);
    }
    if (tid < D_) a1l[tid] = a1;
    __syncthreads();
    float niv = 0.f;
    if (tid < D_) {
        const v4f *agp = (const v4f *)(ws + OFF_AG2P);
        v2f sp = {p.ag_b2[tid], 0.f};
#pragma unroll 4
        for (int k4 = 0; k4 < 32; k4++) {
            v4f x = *(const v4f *)&a1l[4 * k4];
            v4f w = agp[k4 * D_ + tid];
            sp = PKFMA(LO2(x), LO2(w), PKFMA(HI2(x), HI2(w), sp));
        }
        niv = hsum2(sp);
        nil[tid] = niv;
    }
    __syncthreads();
    {   // gate GEMV split: half 0 -> node part (k 0..127), half 1 -> ni part (k 128..255)
        int half = tid >> 7, ch = tid & 127;
        const v4f *gtp = (const v4f *)(ws + OFF_GTP);
        const float *xsrc = half ? nil : &ns[t][0];
        v2f sp = {half ? 0.f : p.gt_b[ch], 0.f};
        int k4base = half * 32;
#pragma unroll 4
        for (int k4 = 0; k4 < 32; k4++) {
            v4f x = *(const v4f *)&xsrc[4 * k4];
            v4f w = gtp[(k4base + k4) * D_ + ch];
            sp = PKFMA(LO2(x), LO2(w), PKFMA(HI2(x), HI2(w), sp));
        }
        gzp[half][ch] = hsum2(sp);
    }
    __syncthreads();
    float upd = 0.f;
    if (tid < D_) {
        float g = sigm(gzp[0][tid] + gzp[1][tid]);
        upd     = g * niv + (1.f - g) * ns[t][tid];
    }
    {   // final LN + store
        float s = wsum64(tid < D_ ? upd : 0.f);
        if (lane == 0) red[wave] = s;
        __syncthreads();
        float mean = (red[0] + red[1]) * (1.f / 128.f);
        __syncthreads();
        float d  = upd - mean;
        float s2 = wsum64(tid < D_ ? d * d : 0.f);
        if (lane == 0) red[wave] = s2;
        __syncthreads();
        float var = (red[0] + red[1]) * (1.f / 128.f);
        if (tid < D_) {
            float o = d * rsqrtf(var + 1e-5f) * p.nn_ln_g[tid] + p.nn_ln_b[tid];
            p.out[((size_t)bs * N_ + t) * D_ + tid] = o;
        }
    }
}

extern "C" void kernel_launch(void* const* d_in, const int* in_sizes, int n_in,
                              void* d_out, int out_size, void* d_ws, size_t ws_size,
                              hipStream_t stream) {
    Params p;
    p.node_states   = (const float*)d_in[0];
    p.edge_features = (const float*)d_in[1];
    p.ee_w1   = (const float*)d_in[2];
    p.ee_b1   = (const float*)d_in[3];
    p.ee_ln_g = (const float*)d_in[4];
    p.ee_ln_b = (const float*)d_in[5];
    p.ee_w2   = (const float*)d_in[6];
    p.ee_b2   = (const float*)d_in[7];
    p.ts_w1   = (const float*)d_in[8];
    p.ts_b1   = (const float*)d_in[9];
    p.ts_ln_g = (const float*)d_in[10];
    p.ts_ln_b = (const float*)d_in[11];
    p.ts_w2   = (const float*)d_in[12];
    p.ts_b2   = (const float*)d_in[13];
    p.ts_w3   = (const float*)d_in[14];
    p.ts_b3   = (const float*)d_in[15];
    p.mc_w1   = (const float*)d_in[16];
    p.mc_b1   = (const float*)d_in[17];
    p.mc_ln_g = (const float*)d_in[18];
    p.mc_ln_b = (const float*)d_in[19];
    p.mc_w2   = (const float*)d_in[20];
    p.mc_b2   = (const float*)d_in[21];
    p.at_in_w  = (const float*)d_in[22];
    p.at_in_b  = (const float*)d_in[23];
    p.at_out_w = (const float*)d_in[24];
    p.at_out_b = (const float*)d_in[25];
    p.ag_w1   = (const float*)d_in[26];
    p.ag_b1   = (const float*)d_in[27];
    p.ag_ln_g = (const float*)d_in[28];
    p.ag_ln_b = (const float*)d_in[29];
    p.ag_w2   = (const float*)d_in[30];
    p.ag_b2   = (const float*)d_in[31];
    p.gt_w    = (const float*)d_in[32];
    p.gt_b    = (const float*)d_in[33];
    p.nn_ln_g = (const float*)d_in[34];
    p.nn_ln_b = (const float*)d_in[35];
    p.mn_ln_g = (const float*)d_in[36];
    p.mn_ln_b = (const float*)d_in[37];
    p.ws      = (float*)d_ws;
    p.out     = (float*)d_out;

    hipLaunchKernelGGL(prep_kernel, dim3((WS_TOTAL + 255) / 256), dim3(256), 0, stream, p);
    hipLaunchKernelGGL(petri_kernel, dim3(B_ * S_ * N_), dim3(256), 0, stream, p);
}

// Round 9
// 504.817 us; speedup vs baseline: 2.1327x; 2.1327x over previous
//
#include <hip/hip_runtime.h>

#define B_  16
#define S_  128
#define N_  13
#define D_  128
#define E_  6
#define M_  64
#define H_  4

typedef float v2f __attribute__((ext_vector_type(2)));
typedef float v4f __attribute__((ext_vector_type(4)));
typedef short v8s __attribute__((ext_vector_type(8)));

#define MFMA16(A, B, C) __builtin_amdgcn_mfma_f32_16x16x32_bf16((A), (B), (C), 0, 0, 0)
#define LDS_ORDER() __asm__ __volatile__("" ::: "memory")

#if __has_builtin(__builtin_elementwise_fma)
#define PKFMA(A, B, C) __builtin_elementwise_fma((A), (B), (C))
#else
#define PKFMA(A, B, C) ((A) * (B) + (C))
#endif
#define LO2(X) __builtin_shufflevector((X), (X), 0, 1)
#define HI2(X) __builtin_shufflevector((X), (X), 2, 3)

// ---- workspace layout ----
// fp32 region (float offsets)
#define F_BTS   0        // folded TS1 bias (64)
#define F_BMC   64       // folded MC1 bias (64)
#define F_AOP   128      // at_out packed k4 (K=64,O=64)   4096
#define F_AG1P  4224     // ag_w1 packed (K=64,O=128)      8192
#define F_AG2P  12416    // ag_w2 packed (K=128,O=128)     16384
#define F_GTP   28800    // gt_w packed (K=256,O=128)      32768
#define F_TOTAL 61568
// bf16 B-fragment region (half offsets from ws+F_TOTAL). frag idx = off/8 + (kc*NT+T)*64 + lane
#define H_EE1   0        // ee_w1    K=6->1 chunk, NT=4    2048
#define H_WTS   2048     // ee_w2@ts_w1 folded, 2 ch, NT=4 4096
#define H_TS2   6144     // ts_w2    2 ch, NT=2            2048
#define H_MC1   8192     // mc_w1[0:128] 4 ch, NT=4        8192
#define H_WMCE  16384    // ee_w2@mc_w1[128:] 2 ch, NT=4   4096
#define H_MC2   20480    // mc_w2    2 ch, NT=4            4096
#define H_ATI   24576    // at_in_w  2 ch, NT=12           12288
#define H_TOTAL 36864

__device__ __forceinline__ v2f mkpair(float a, float b) { v2f r; r.x = a; r.y = b; return r; }

__device__ __forceinline__ unsigned short f2bs(float x) {  // RTNE fp32->bf16
    unsigned u = __float_as_uint(x);
    u += 0x7FFFu + ((u >> 16) & 1u);
    return (unsigned short)(u >> 16);
}
__device__ __forceinline__ float erf_fast(float x) {  // A&S 7.1.26, |eps|<1.5e-7
    float ax = fabsf(x);
    float t  = __builtin_amdgcn_rcpf(fmaf(0.3275911f, ax, 1.0f));
    float p  = t * fmaf(t, fmaf(t, fmaf(t, fmaf(t, 1.061405429f, -1.453152027f),
                                        1.421413741f), -0.284496736f), 0.254829592f);
    float r  = fmaf(-p, __expf(-ax * ax), 1.0f);
    return copysignf(r, x);
}
__device__ __forceinline__ float geluf(float x) {
    return 0.5f * x * (1.0f + erf_fast(x * 0.7071067811865475f));
}
__device__ __forceinline__ float sigm(float x) { return 1.0f / (1.0f + __expf(-x)); }
__device__ __forceinline__ v4f gelu4(v4f x) {
    v4f r; r[0] = geluf(x[0]); r[1] = geluf(x[1]); r[2] = geluf(x[2]); r[3] = geluf(x[3]);
    return r;
}

// LN over 64 channels in MFMA C-layout: 4 tiles (N=16 each) x 4 rows/lane.
// Channels of one row live in 4 tile-regs x 16 lanes of the quad-group.
template <bool DOGELU>
__device__ __forceinline__ void ln_c64(v4f &a0, v4f &a1, v4f &a2, v4f &a3,
                                       float g0, float g1, float g2, float g3,
                                       float b0, float b1, float b2, float b3) {
    v4f s = a0 + a1 + a2 + a3;
    v4f q = a0 * a0 + a1 * a1 + a2 * a2 + a3 * a3;
#pragma unroll
    for (int o = 1; o < 16; o <<= 1) {
#pragma unroll
        for (int r = 0; r < 4; r++) {
            s[r] += __shfl_xor(s[r], o, 64);
            q[r] += __shfl_xor(q[r], o, 64);
        }
    }
    v4f mean = s * 0.015625f;
    v4f rs;
#pragma unroll
    for (int r = 0; r < 4; r++) {
        float var = fmaxf(q[r] * 0.015625f - mean[r] * mean[r], 0.f);
        rs[r] = rsqrtf(var + 1e-5f);
    }
    a0 = (a0 - mean) * rs * g0 + b0;
    a1 = (a1 - mean) * rs * g1 + b1;
    a2 = (a2 - mean) * rs * g2 + b2;
    a3 = (a3 - mean) * rs * g3 + b3;
    if (DOGELU) { a0 = gelu4(a0); a1 = gelu4(a1); a2 = gelu4(a2); a3 = gelu4(a3); }
}

// LN over 128 channels, 2 values/lane across full wave
template <bool DOGELU>
__device__ __forceinline__ void ln128(float &x0, float &x1, float g0_, float g1_,
                                      float b0_, float b1_) {
    float s = x0 + x1, q = x0 * x0 + x1 * x1;
#pragma unroll
    for (int o = 1; o < 64; o <<= 1) { s += __shfl_xor(s, o, 64); q += __shfl_xor(q, o, 64); }
    float mean = s * (1.f / 128.f);
    float var  = fmaxf(q * (1.f / 128.f) - mean * mean, 0.f);
    float rs   = rsqrtf(var + 1e-5f);
    x0 = (x0 - mean) * rs * g0_ + b0_;
    x1 = (x1 - mean) * rs * g1_ + b1_;
    if (DOGELU) { x0 = geluf(x0); x1 = geluf(x1); }
}

// write C-layout tiles as bf16 row-major [m][ch] into xp (16 ds_write_b16)
__device__ __forceinline__ void store_c(unsigned short (*xr)[136], int colbase, int L,
                                        v4f a0, v4f a1, v4f a2, v4f a3) {
    const int c = L & 15, g = L >> 4;
#pragma unroll
    for (int r = 0; r < 4; r++) {
        xr[4 * g + r][colbase + c]      = f2bs(a0[r]);
        xr[4 * g + r][colbase + 16 + c] = f2bs(a1[r]);
        xr[4 * g + r][colbase + 32 + c] = f2bs(a2[r]);
        xr[4 * g + r][colbase + 48 + c] = f2bs(a3[r]);
    }
}

__device__ __forceinline__ v8s pack8(v4f lo, v4f hi) {
    v8s r;
    r[0] = (short)f2bs(lo[0]); r[1] = (short)f2bs(lo[1]);
    r[2] = (short)f2bs(lo[2]); r[3] = (short)f2bs(lo[3]);
    r[4] = (short)f2bs(hi[0]); r[5] = (short)f2bs(hi[1]);
    r[6] = (short)f2bs(hi[2]); r[7] = (short)f2bs(hi[3]);
    return r;
}

struct Params {
    const float *node_states, *edge_features;
    const float *ee_w1, *ee_b1, *ee_ln_g, *ee_ln_b, *ee_w2, *ee_b2;
    const float *ts_w1, *ts_b1, *ts_ln_g, *ts_ln_b, *ts_w2, *ts_b2, *ts_w3, *ts_b3;
    const float *mc_w1, *mc_b1, *mc_ln_g, *mc_ln_b, *mc_w2, *mc_b2;
    const float *at_in_w, *at_in_b, *at_out_w, *at_out_b;
    const float *ag_w1, *ag_b1, *ag_ln_g, *ag_ln_b, *ag_w2, *ag_b2;
    const float *gt_w, *gt_b, *nn_ln_g, *nn_ln_b, *mn_ln_g, *mn_ln_b;
    float *ws;
    float *out;
};

// ---- prep: fold enc matrices; pack edge weights into bf16 B-fragments;
//      pack node-phase weights k4-contiguous fp32 (R8-verified scheme) ----
__global__ __launch_bounds__(256) void prep_kernel(Params p) {
    int i = blockIdx.x * 256 + threadIdx.x;
    if (i < F_TOTAL) {
        float v;
        if (i < F_BMC) {                 // folded TS1 bias
            int o = i - F_BTS;
            float s = p.ts_b1[o];
            for (int e = 0; e < E_; e++) s += p.ee_b2[e] * p.ts_w1[e * M_ + o];
            v = s;
        } else if (i < F_AOP) {          // folded MC1 bias
            int o = i - F_BMC;
            float s = p.mc_b1[o];
            for (int e = 0; e < E_; e++) s += p.ee_b2[e] * p.mc_w1[(D_ + e) * M_ + o];
            v = s;
        } else if (i < F_AG1P) {
            int x = i - F_AOP, r = x >> 2, kk = x & 3, k4 = r >> 6, ch = r & 63;
            v = p.at_out_w[(4 * k4 + kk) * M_ + ch];
        } else if (i < F_AG2P) {
            int x = i - F_AG1P, r = x >> 2, kk = x & 3, k4 = r >> 7, ch = r & 127;
            v = p.ag_w1[(4 * k4 + kk) * D_ + ch];
        } else if (i < F_GTP) {
            int x = i - F_AG2P, r = x >> 2, kk = x & 3, k4 = r >> 7, ch = r & 127;
            v = p.ag_w2[(4 * k4 + kk) * D_ + ch];
        } else {
            int x = i - F_GTP, r = x >> 2, kk = x & 3, k4 = r >> 7, ch = r & 127;
            v = p.gt_w[(4 * k4 + kk) * D_ + ch];
        }
        p.ws[i] = v;
        return;
    }
    int hi = i - F_TOTAL;
    if (hi >= H_TOTAL) return;
    unsigned short *wsh = (unsigned short *)(p.ws + F_TOTAL);
    int base, NT;
    const int region =
        (hi < H_WTS) ? 0 : (hi < H_TS2) ? 1 : (hi < H_MC1) ? 2 :
        (hi < H_WMCE) ? 3 : (hi < H_MC2) ? 4 : (hi < H_ATI) ? 5 : 6;
    switch (region) {
        case 0: base = H_EE1;  NT = 4;  break;
        case 1: base = H_WTS;  NT = 4;  break;
        case 2: base = H_TS2;  NT = 2;  break;
        case 3: base = H_MC1;  NT = 4;  break;
        case 4: base = H_WMCE; NT = 4;  break;
        case 5: base = H_MC2;  NT = 4;  break;
        default: base = H_ATI; NT = 12; break;
    }
    int r0 = hi - base;
    int j  = r0 & 7, L = (r0 >> 3) & 63, tk = r0 >> 9;
    int kc = tk / NT, T = tk - kc * NT;
    int c  = L & 15, gg = L >> 4;
    int k  = 32 * kc + 8 * gg + j;
    int n  = 16 * T + c;
    float v = 0.f;
    switch (region) {
        case 0: v = (k < E_) ? p.ee_w1[k * M_ + n] : 0.f; break;
        case 1: { float s = 0.f;
                  for (int e = 0; e < E_; e++) s += p.ee_w2[k * E_ + e] * p.ts_w1[e * M_ + n];
                  v = s; } break;
        case 2: v = p.ts_w2[k * 32 + n]; break;
        case 3: v = p.mc_w1[k * M_ + n]; break;
        case 4: { float s = 0.f;
                  for (int e = 0; e < E_; e++) s += p.ee_w2[k * E_ + e] * p.mc_w1[(D_ + e) * M_ + n];
                  v = s; } break;
        case 5: v = p.mc_w2[k * M_ + n]; break;
        default: v = p.at_in_w[k * 192 + n]; break;
    }
    wsh[hi] = f2bs(v);
}

#define SPL4(NAME, EXPR) v4f NAME; { float _b = (EXPR); NAME = (v4f){_b, _b, _b, _b}; }

// one wave per (b,s,target). Edge phase via 16x16x32 bf16 MFMA (M=13->16 edges),
// LN/softmax in C-layout regs, layout transposes through per-wave LDS.
// Rows 13..15 carry bounded garbage, confined (row-local LN, masked softmax/colsum).
__global__ __launch_bounds__(256) void petri_kernel(Params p) {
    const int tid = threadIdx.x;
    const int w   = tid >> 6;
    const int L   = tid & 63;
    const int c   = L & 15, g = L >> 4;
    const int task = blockIdx.x * 4 + w;       // 0 .. B*S*N-1
    const int bs = task / N_, t = task - bs * N_;
    const int mrow = (c < N_) ? c : 0;         // clamped A-row (rows>=13 discarded)

    __shared__ unsigned short xp[4][16][136];  // per-wave transpose buffer (bf16)
    __shared__ float xv[4][256];               // per-wave node-phase staging

    const float *ws = p.ws;
    const v8s *wb = (const v8s *)((const unsigned short *)(ws + F_TOTAL));
    const v8s zf = {0, 0, 0, 0, 0, 0, 0, 0};

    // =========== E1: h = gelu(LN(ef @ ee_w1 + b)) ===========
    SPL4(h0, p.ee_b1[c]); SPL4(h1, p.ee_b1[16 + c]);
    SPL4(h2, p.ee_b1[32 + c]); SPL4(h3, p.ee_b1[48 + c]);
    {
        v8s a = zf;
        if (g == 0) {
            const float *efp = p.edge_features + (((size_t)bs * N_ + mrow) * N_ + t) * E_;
            const v2f *e2 = (const v2f *)efp;   // 8B-aligned (24B row stride)
            v2f fa = e2[0], fb = e2[1], fc = e2[2];
            a[0] = (short)f2bs(fa.x); a[1] = (short)f2bs(fa.y);
            a[2] = (short)f2bs(fb.x); a[3] = (short)f2bs(fb.y);
            a[4] = (short)f2bs(fc.x); a[5] = (short)f2bs(fc.y);
        }
        h0 = MFMA16(a, wb[0 * 64 + L], h0);
        h1 = MFMA16(a, wb[1 * 64 + L], h1);
        h2 = MFMA16(a, wb[2 * 64 + L], h2);
        h3 = MFMA16(a, wb[3 * 64 + L], h3);
    }
    ln_c64<true>(h0, h1, h2, h3,
                 p.ee_ln_g[c], p.ee_ln_g[16 + c], p.ee_ln_g[32 + c], p.ee_ln_g[48 + c],
                 p.ee_ln_b[c], p.ee_ln_b[16 + c], p.ee_ln_b[32 + c], p.ee_ln_b[48 + c]);
    store_c(xp[w], 64, L, h0, h1, h2, h3);     // h persists at cols 64..127
    LDS_ORDER();
    v8s ah0 = *(const v8s *)&xp[w][c][64 + 8 * g];
    v8s ah1 = *(const v8s *)&xp[w][c][96 + 8 * g];

    // =========== TS1 (enc folded): t1 = gelu(LN(h @ W_ts + b_ts)) ===========
    v4f tsv;
    {
        SPL4(t0, ws[F_BTS + c]); SPL4(t1, ws[F_BTS + 16 + c]);
        SPL4(t2, ws[F_BTS + 32 + c]); SPL4(t3, ws[F_BTS + 48 + c]);
        t0 = MFMA16(ah0, wb[256 + 0 * 64 + L], t0); t0 = MFMA16(ah1, wb[256 + 4 * 64 + L], t0);
        t1 = MFMA16(ah0, wb[256 + 1 * 64 + L], t1); t1 = MFMA16(ah1, wb[256 + 5 * 64 + L], t1);
        t2 = MFMA16(ah0, wb[256 + 2 * 64 + L], t2); t2 = MFMA16(ah1, wb[256 + 6 * 64 + L], t2);
        t3 = MFMA16(ah0, wb[256 + 3 * 64 + L], t3); t3 = MFMA16(ah1, wb[256 + 7 * 64 + L], t3);
        ln_c64<true>(t0, t1, t2, t3,
                     p.ts_ln_g[c], p.ts_ln_g[16 + c], p.ts_ln_g[32 + c], p.ts_ln_g[48 + c],
                     p.ts_ln_b[c], p.ts_ln_b[16 + c], p.ts_ln_b[32 + c], p.ts_ln_b[48 + c]);
        store_c(xp[w], 0, L, t0, t1, t2, t3);
        LDS_ORDER();
        v8s at0 = *(const v8s *)&xp[w][c][0 + 8 * g];
        v8s at1 = *(const v8s *)&xp[w][c][32 + 8 * g];
        // TS2/TS3: 32-dim hidden -> scalar sigmoid gate per edge
        SPL4(u0, p.ts_b2[c]); SPL4(u1, p.ts_b2[16 + c]);
        u0 = MFMA16(at0, wb[768 + 0 * 64 + L], u0); u0 = MFMA16(at1, wb[768 + 2 * 64 + L], u0);
        u1 = MFMA16(at0, wb[768 + 1 * 64 + L], u1); u1 = MFMA16(at1, wb[768 + 3 * 64 + L], u1);
        float w3a = p.ts_w3[c], w3b = p.ts_w3[16 + c], b3 = p.ts_b3[0];
        v4f d = gelu4(u0) * w3a + gelu4(u1) * w3b;
#pragma unroll
        for (int o = 1; o < 16; o <<= 1)
#pragma unroll
            for (int r = 0; r < 4; r++) d[r] += __shfl_xor(d[r], o, 64);
#pragma unroll
        for (int r = 0; r < 4; r++) tsv[r] = sigm(d[r] + b3);
    }

    // =========== MC1: mh = gelu(LN(ns @ mc_w1[:128] + h @ W_mce + b)) ===========
    v8s am0, am1;
    {
        SPL4(m0, ws[F_BMC + c]); SPL4(m1, ws[F_BMC + 16 + c]);
        SPL4(m2, ws[F_BMC + 32 + c]); SPL4(m3, ws[F_BMC + 48 + c]);
        const float *nsr = p.node_states + ((size_t)bs * N_ + mrow) * D_;
#pragma unroll
        for (int kc = 0; kc < 4; kc++) {
            v4f xlo = *(const v4f *)(nsr + 32 * kc + 8 * g);
            v4f xhi = *(const v4f *)(nsr + 32 * kc + 8 * g + 4);
            v8s an = pack8(xlo, xhi);
            m0 = MFMA16(an, wb[1024 + (kc * 4 + 0) * 64 + L], m0);
            m1 = MFMA16(an, wb[1024 + (kc * 4 + 1) * 64 + L], m1);
            m2 = MFMA16(an, wb[1024 + (kc * 4 + 2) * 64 + L], m2);
            m3 = MFMA16(an, wb[1024 + (kc * 4 + 3) * 64 + L], m3);
        }
        m0 = MFMA16(ah0, wb[2048 + 0 * 64 + L], m0); m0 = MFMA16(ah1, wb[2048 + 4 * 64 + L], m0);
        m1 = MFMA16(ah0, wb[2048 + 1 * 64 + L], m1); m1 = MFMA16(ah1, wb[2048 + 5 * 64 + L], m1);
        m2 = MFMA16(ah0, wb[2048 + 2 * 64 + L], m2); m2 = MFMA16(ah1, wb[2048 + 6 * 64 + L], m2);
        m3 = MFMA16(ah0, wb[2048 + 3 * 64 + L], m3); m3 = MFMA16(ah1, wb[2048 + 7 * 64 + L], m3);
        ln_c64<true>(m0, m1, m2, m3,
                     p.mc_ln_g[c], p.mc_ln_g[16 + c], p.mc_ln_g[32 + c], p.mc_ln_g[48 + c],
                     p.mc_ln_b[c], p.mc_ln_b[16 + c], p.mc_ln_b[32 + c], p.mc_ln_b[48 + c]);
        store_c(xp[w], 0, L, m0, m1, m2, m3);  // mh (t1 consumed)
        LDS_ORDER();
        am0 = *(const v8s *)&xp[w][c][0 + 8 * g];
        am1 = *(const v8s *)&xp[w][c][32 + 8 * g];
    }

    // =========== MC2: wm = LN((mh @ mc_w2 + b) * ts) ===========
    v8s aw0, aw1;
    {
        SPL4(x0, p.mc_b2[c]); SPL4(x1, p.mc_b2[16 + c]);
        SPL4(x2, p.mc_b2[32 + c]); SPL4(x3, p.mc_b2[48 + c]);
        x0 = MFMA16(am0, wb[2560 + 0 * 64 + L], x0); x0 = MFMA16(am1, wb[2560 + 4 * 64 + L], x0);
        x1 = MFMA16(am0, wb[2560 + 1 * 64 + L], x1); x1 = MFMA16(am1, wb[2560 + 5 * 64 + L], x1);
        x2 = MFMA16(am0, wb[2560 + 2 * 64 + L], x2); x2 = MFMA16(am1, wb[2560 + 6 * 64 + L], x2);
        x3 = MFMA16(am0, wb[2560 + 3 * 64 + L], x3); x3 = MFMA16(am1, wb[2560 + 7 * 64 + L], x3);
        x0 *= tsv; x1 *= tsv; x2 *= tsv; x3 *= tsv;   // rows aligned: both r-indexed
        ln_c64<false>(x0, x1, x2, x3,
                      p.mn_ln_g[c], p.mn_ln_g[16 + c], p.mn_ln_g[32 + c], p.mn_ln_g[48 + c],
                      p.mn_ln_b[c], p.mn_ln_b[16 + c], p.mn_ln_b[32 + c], p.mn_ln_b[48 + c]);
        store_c(xp[w], 0, L, x0, x1, x2, x3);  // wm (mh consumed)
        LDS_ORDER();
        aw0 = *(const v8s *)&xp[w][c][0 + 8 * g];
        aw1 = *(const v8s *)&xp[w][c][32 + 8 * g];
    }

    // =========== AT: qkv = wm @ at_in_w + b (12 N-tiles) ===========
    v4f qt0, qt1, qt2, qt3, kt0, kt1, kt2, kt3, vt0, vt1, vt2, vt3;
    {
#define ATACC(ACC, T)                                                    \
        { float _b = p.at_in_b[16 * (T) + c]; ACC = (v4f){_b, _b, _b, _b}; \
          ACC = MFMA16(aw0, wb[3072 + (0 * 12 + (T)) * 64 + L], ACC);      \
          ACC = MFMA16(aw1, wb[3072 + (1 * 12 + (T)) * 64 + L], ACC); }
        ATACC(qt0, 0) ATACC(qt1, 1) ATACC(qt2, 2) ATACC(qt3, 3)
        ATACC(kt0, 4) ATACC(kt1, 5) ATACC(kt2, 6) ATACC(kt3, 7)
        ATACC(vt0, 8) ATACC(vt1, 9) ATACC(vt2, 10) ATACC(vt3, 11)
#undef ATACC
    }

    // =========== attention: S_h = Q_h K_h^T via MFMA, softmax, colsum, PV ===========
    float aggh0, aggh1, aggh2, aggh3;   // aggp[16h + c]
    {
        store_c(xp[w], 0, L, qt0, qt1, qt2, qt3);    // Q at cols 0..63
        store_c(xp[w], 64, L, kt0, kt1, kt2, kt3);   // K at cols 64..127
        LDS_ORDER();
        v4f s0, s1, s2, s3;
        {
            const v4f z4 = {0.f, 0.f, 0.f, 0.f};
            v8s aq, bk;
            aq = (g < 2) ? *(const v8s *)&xp[w][c][0 + 8 * g] : zf;
            bk = (g < 2) ? *(const v8s *)&xp[w][c][64 + 0 + 8 * g] : zf;
            s0 = MFMA16(aq, bk, z4);
            aq = (g < 2) ? *(const v8s *)&xp[w][c][16 + 8 * g] : zf;
            bk = (g < 2) ? *(const v8s *)&xp[w][c][64 + 16 + 8 * g] : zf;
            s1 = MFMA16(aq, bk, z4);
            aq = (g < 2) ? *(const v8s *)&xp[w][c][32 + 8 * g] : zf;
            bk = (g < 2) ? *(const v8s *)&xp[w][c][64 + 32 + 8 * g] : zf;
            s2 = MFMA16(aq, bk, z4);
            aq = (g < 2) ? *(const v8s *)&xp[w][c][48 + 8 * g] : zf;
            bk = (g < 2) ? *(const v8s *)&xp[w][c][64 + 48 + 8 * g] : zf;
            s3 = MFMA16(aq, bk, z4);
        }
        if (c >= N_) {   // mask source columns 13..15
            v4f neg = {-1e30f, -1e30f, -1e30f, -1e30f};
            s0 = neg; s1 = neg; s2 = neg; s3 = neg;
        }
        v4f m0 = s0, m1 = s1, m2 = s2, m3 = s3;
#pragma unroll
        for (int o = 1; o < 16; o <<= 1)
#pragma unroll
            for (int r = 0; r < 4; r++) {
                m0[r] = fmaxf(m0[r], __shfl_xor(m0[r], o, 64));
                m1[r] = fmaxf(m1[r], __shfl_xor(m1[r], o, 64));
                m2[r] = fmaxf(m2[r], __shfl_xor(m2[r], o, 64));
                m3[r] = fmaxf(m3[r], __shfl_xor(m3[r], o, 64));
            }
        v4f e0, e1, e2, e3;
#pragma unroll
        for (int r = 0; r < 4; r++) {
            e0[r] = __expf((s0[r] - m0[r]) * 0.25f);
            e1[r] = __expf((s1[r] - m1[r]) * 0.25f);
            e2[r] = __expf((s2[r] - m2[r]) * 0.25f);
            e3[r] = __expf((s3[r] - m3[r]) * 0.25f);
        }
        v4f z0 = e0, z1 = e1, z2 = e2, z3 = e3;
#pragma unroll
        for (int o = 1; o < 16; o <<= 1)
#pragma unroll
            for (int r = 0; r < 4; r++) {
                z0[r] += __shfl_xor(z0[r], o, 64);
                z1[r] += __shfl_xor(z1[r], o, 64);
                z2[r] += __shfl_xor(z2[r], o, 64);
                z3[r] += __shfl_xor(z3[r], o, 64);
            }
#pragma unroll
        for (int r = 0; r < 4; r++) {
            e0[r] *= __builtin_amdgcn_rcpf(z0[r]);
            e1[r] *= __builtin_amdgcn_rcpf(z1[r]);
            e2[r] *= __builtin_amdgcn_rcpf(z2[r]);
            e3[r] *= __builtin_amdgcn_rcpf(z3[r]);
        }
        // colsum over q rows (exclude rows >= 13)
        int row0 = 4 * g;
        float cs0 = e0[0], cs1 = e1[0], cs2 = e2[0], cs3 = e3[0];
#pragma unroll
        for (int r = 1; r < 4; r++) {
            bool ok = (row0 + r) < N_;
            cs0 += ok ? e0[r] : 0.f; cs1 += ok ? e1[r] : 0.f;
            cs2 += ok ? e2[r] : 0.f; cs3 += ok ? e3[r] : 0.f;
        }
        cs0 += __shfl_xor(cs0, 16, 64); cs0 += __shfl_xor(cs0, 32, 64);
        cs1 += __shfl_xor(cs1, 16, 64); cs1 += __shfl_xor(cs1, 32, 64);
        cs2 += __shfl_xor(cs2, 16, 64); cs2 += __shfl_xor(cs2, 32, 64);
        cs3 += __shfl_xor(cs3, 16, 64); cs3 += __shfl_xor(cs3, 32, 64);
        // PV: aggp[ch] = (1/13) sum_ks cs[ks] * V[ks][ch]
        int pbase = (((L & 48) + ((L & 48) >> 2)) << 2);  // byte addr of lane 16g+4g
        aggh0 = 0.f; aggh1 = 0.f; aggh2 = 0.f; aggh3 = 0.f;
#pragma unroll
        for (int r = 0; r < 4; r++) {
            int pa = pbase + 4 * r;
            float c0 = __int_as_float(__builtin_amdgcn_ds_bpermute(pa, __float_as_int(cs0)));
            float c1 = __int_as_float(__builtin_amdgcn_ds_bpermute(pa, __float_as_int(cs1)));
            float c2 = __int_as_float(__builtin_amdgcn_ds_bpermute(pa, __float_as_int(cs2)));
            float c3 = __int_as_float(__builtin_amdgcn_ds_bpermute(pa, __float_as_int(cs3)));
            aggh0 += c0 * vt0[r]; aggh1 += c1 * vt1[r];
            aggh2 += c2 * vt2[r]; aggh3 += c3 * vt3[r];
        }
        aggh0 += __shfl_xor(aggh0, 16, 64); aggh0 += __shfl_xor(aggh0, 32, 64);
        aggh1 += __shfl_xor(aggh1, 16, 64); aggh1 += __shfl_xor(aggh1, 32, 64);
        aggh2 += __shfl_xor(aggh2, 16, 64); aggh2 += __shfl_xor(aggh2, 32, 64);
        aggh3 += __shfl_xor(aggh3, 16, 64); aggh3 += __shfl_xor(aggh3, 32, 64);
        const float inv13 = 1.0f / 13.0f;
        aggh0 *= inv13; aggh1 *= inv13; aggh2 *= inv13; aggh3 *= inv13;
    }

    // =========== node phase (fp32 packed GEMVs, per wave) ===========
    if (g == 0) {
        xv[w][c]      = aggh0; xv[w][16 + c] = aggh1;
        xv[w][32 + c] = aggh2; xv[w][48 + c] = aggh3;
    }
    LDS_ORDER();
    // at_out (after mean, by linearity)
    float agg2v;
    {
        const v4f *AO = (const v4f *)(ws + F_AOP);
        v2f sp = mkpair(p.at_out_b[L], 0.f);
#pragma unroll 4
        for (int k4 = 0; k4 < 16; k4++) {
            v4f x = *(const v4f *)&xv[w][4 * k4];
            v4f wv = AO[k4 * 64 + L];
            sp = PKFMA(LO2(x), LO2(wv), PKFMA(HI2(x), HI2(wv), sp));
        }
        agg2v = sp.x + sp.y;
        xv[w][64 + L] = agg2v;
    }
    LDS_ORDER();
    // ag1 -> LN -> gelu
    float a1_0, a1_1;
    {
        const v4f *AG = (const v4f *)(ws + F_AG1P);
        v2f p0 = mkpair(p.ag_b1[L], 0.f), p1 = mkpair(p.ag_b1[L + 64], 0.f);
#pragma unroll 4
        for (int k4 = 0; k4 < 16; k4++) {
            v4f x = *(const v4f *)&xv[w][64 + 4 * k4];
            v4f w0 = AG[k4 * 128 + L], w1 = AG[k4 * 128 + 64 + L];
            p0 = PKFMA(LO2(x), LO2(w0), PKFMA(HI2(x), HI2(w0), p0));
            p1 = PKFMA(LO2(x), LO2(w1), PKFMA(HI2(x), HI2(w1), p1));
        }
        a1_0 = p0.x + p0.y; a1_1 = p1.x + p1.y;
        ln128<true>(a1_0, a1_1, p.ag_ln_g[L], p.ag_ln_g[L + 64],
                    p.ag_ln_b[L], p.ag_ln_b[L + 64]);
        xv[w][128 + L] = a1_0; xv[w][192 + L] = a1_1;
    }
    LDS_ORDER();
    // ag2
    float niv0, niv1;
    {
        const v4f *AG = (const v4f *)(ws + F_AG2P);
        v2f p0 = mkpair(p.ag_b2[L], 0.f), p1 = mkpair(p.ag_b2[L + 64], 0.f);
#pragma unroll 8
        for (int k4 = 0; k4 < 32; k4++) {
            v4f x = *(const v4f *)&xv[w][128 + 4 * k4];
            v4f w0 = AG[k4 * 128 + L], w1 = AG[k4 * 128 + 64 + L];
            p0 = PKFMA(LO2(x), LO2(w0), PKFMA(HI2(x), HI2(w0), p0));
            p1 = PKFMA(LO2(x), LO2(w1), PKFMA(HI2(x), HI2(w1), p1));
        }
        niv0 = p0.x + p0.y; niv1 = p1.x + p1.y;
    }
    // stage gate input: [ns_t | nil]
    const float *nst = p.node_states + ((size_t)bs * N_ + t) * D_;
    float n0 = nst[L], n1 = nst[L + 64];
    xv[w][L] = n0; xv[w][64 + L] = n1;          // overwrite aggp/agg2 (dead)
    xv[w][128 + L] = niv0; xv[w][192 + L] = niv1;  // overwrite a1l after ag2 reads
    LDS_ORDER();
    // gate GEMV K=256
    float upd0, upd1;
    {
        const v4f *GT = (const v4f *)(ws + F_GTP);
        v2f p0 = mkpair(p.gt_b[L], 0.f), p1 = mkpair(p.gt_b[L + 64], 0.f);
#pragma unroll 8
        for (int k4 = 0; k4 < 64; k4++) {
            v4f x = *(const v4f *)&xv[w][4 * k4];
            v4f w0 = GT[k4 * 128 + L], w1 = GT[k4 * 128 + 64 + L];
            p0 = PKFMA(LO2(x), LO2(w0), PKFMA(HI2(x), HI2(w0), p0));
            p1 = PKFMA(LO2(x), LO2(w1), PKFMA(HI2(x), HI2(w1), p1));
        }
        float g0 = sigm(p0.x + p0.y), g1 = sigm(p1.x + p1.y);
        upd0 = g0 * niv0 + (1.f - g0) * n0;
        upd1 = g1 * niv1 + (1.f - g1) * n1;
    }
    // final LN + store
    ln128<false>(upd0, upd1, p.nn_ln_g[L], p.nn_ln_g[L + 64],
                 p.nn_ln_b[L], p.nn_ln_b[L + 64]);
    float *op = p.out + ((size_t)bs * N_ + t) * D_;
    op[L] = upd0; op[L + 64] = upd1;
}

extern "C" void kernel_launch(void* const* d_in, const int* in_sizes, int n_in,
                              void* d_out, int out_size, void* d_ws, size_t ws_size,
                              hipStream_t stream) {
    Params p;
    p.node_states   = (const float*)d_in[0];
    p.edge_features = (const float*)d_in[1];
    p.ee_w1   = (const float*)d_in[2];
    p.ee_b1   = (const float*)d_in[3];
    p.ee_ln_g = (const float*)d_in[4];
    p.ee_ln_b = (const float*)d_in[5];
    p.ee_w2   = (const float*)d_in[6];
    p.ee_b2   = (const float*)d_in[7];
    p.ts_w1   = (const float*)d_in[8];
    p.ts_b1   = (const float*)d_in[9];
    p.ts_ln_g = (const float*)d_in[10];
    p.ts_ln_b = (const float*)d_in[11];
    p.ts_w2   = (const float*)d_in[12];
    p.ts_b2   = (const float*)d_in[13];
    p.ts_w3   = (const float*)d_in[14];
    p.ts_b3   = (const float*)d_in[15];
    p.mc_w1   = (const float*)d_in[16];
    p.mc_b1   = (const float*)d_in[17];
    p.mc_ln_g = (const float*)d_in[18];
    p.mc_ln_b = (const float*)d_in[19];
    p.mc_w2   = (const float*)d_in[20];
    p.mc_b2   = (const float*)d_in[21];
    p.at_in_w  = (const float*)d_in[22];
    p.at_in_b  = (const float*)d_in[23];
    p.at_out_w = (const float*)d_in[24];
    p.at_out_b = (const float*)d_in[25];
    p.ag_w1   = (const float*)d_in[26];
    p.ag_b1   = (const float*)d_in[27];
    p.ag_ln_g = (const float*)d_in[28];
    p.ag_ln_b = (const float*)d_in[29];
    p.ag_w2   = (const float*)d_in[30];
    p.ag_b2   = (const float*)d_in[31];
    p.gt_w    = (const float*)d_in[32];
    p.gt_b    = (const float*)d_in[33];
    p.nn_ln_g = (const float*)d_in[34];
    p.nn_ln_b = (const float*)d_in[35];
    p.mn_ln_g = (const float*)d_in[36];
    p.mn_ln_b = (const float*)d_in[37];
    p.ws      = (float*)d_ws;
    p.out     = (float*)d_out;

    const int prep_threads = F_TOTAL + H_TOTAL;
    hipLaunchKernelGGL(prep_kernel, dim3((prep_threads + 255) / 256), dim3(256), 0, stream, p);
    hipLaunchKernelGGL(petri_kernel, dim3((B_ * S_ * N_) / 4), dim3(256), 0, stream, p);
}

// Round 10
// 434.619 us; speedup vs baseline: 2.4772x; 1.1615x over previous
//
#include <hip/hip_runtime.h>

#define B_  16
#define S_  128
#define N_  13
#define D_  128
#define E_  6
#define M_  64
#define H_  4

typedef float v2f __attribute__((ext_vector_type(2)));
typedef float v4f __attribute__((ext_vector_type(4)));
typedef short v8s __attribute__((ext_vector_type(8)));

#define MFMA16(A, B, C) __builtin_amdgcn_mfma_f32_16x16x32_bf16((A), (B), (C), 0, 0, 0)
#define LDS_ORDER() __asm__ __volatile__("" ::: "memory")

#if __has_builtin(__builtin_elementwise_fma)
#define PKFMA(A, B, C) __builtin_elementwise_fma((A), (B), (C))
#else
#define PKFMA(A, B, C) ((A) * (B) + (C))
#endif
#define LO2(X) __builtin_shufflevector((X), (X), 0, 1)
#define HI2(X) __builtin_shufflevector((X), (X), 2, 3)

// ---- workspace layout ----
#define F_BTS   0
#define F_BMC   64
#define F_AOP   128
#define F_AG1P  4224
#define F_AG2P  12416
#define F_GTP   28800
#define F_TOTAL 61568
#define H_EE1   0
#define H_WTS   2048
#define H_TS2   6144
#define H_MC1   8192
#define H_WMCE  16384
#define H_MC2   20480
#define H_ATI   24576
#define H_TOTAL 36864

__device__ __forceinline__ v2f mkpair(float a, float b) { v2f r; r.x = a; r.y = b; return r; }

__device__ __forceinline__ unsigned short f2bs(float x) {  // RTNE fp32->bf16
    unsigned u = __float_as_uint(x);
    u += 0x7FFFu + ((u >> 16) & 1u);
    return (unsigned short)(u >> 16);
}
__device__ __forceinline__ float erf_fast(float x) {  // A&S 7.1.26, |eps|<1.5e-7
    float ax = fabsf(x);
    float t  = __builtin_amdgcn_rcpf(fmaf(0.3275911f, ax, 1.0f));
    float p  = t * fmaf(t, fmaf(t, fmaf(t, fmaf(t, 1.061405429f, -1.453152027f),
                                        1.421413741f), -0.284496736f), 0.254829592f);
    float r  = fmaf(-p, __expf(-ax * ax), 1.0f);
    return copysignf(r, x);
}
__device__ __forceinline__ float geluf(float x) {
    return 0.5f * x * (1.0f + erf_fast(x * 0.7071067811865475f));
}
__device__ __forceinline__ float sigm(float x) { return 1.0f / (1.0f + __expf(-x)); }
__device__ __forceinline__ v4f gelu4(v4f x) {
    v4f r; r[0] = geluf(x[0]); r[1] = geluf(x[1]); r[2] = geluf(x[2]); r[3] = geluf(x[3]);
    return r;
}

template <bool DOGELU>
__device__ __forceinline__ void ln_c64(v4f &a0, v4f &a1, v4f &a2, v4f &a3,
                                       float g0, float g1, float g2, float g3,
                                       float b0, float b1, float b2, float b3) {
    v4f s = a0 + a1 + a2 + a3;
    v4f q = a0 * a0 + a1 * a1 + a2 * a2 + a3 * a3;
#pragma unroll
    for (int o = 1; o < 16; o <<= 1) {
#pragma unroll
        for (int r = 0; r < 4; r++) {
            s[r] += __shfl_xor(s[r], o, 64);
            q[r] += __shfl_xor(q[r], o, 64);
        }
    }
    v4f mean = s * 0.015625f;
    v4f rs;
#pragma unroll
    for (int r = 0; r < 4; r++) {
        float var = fmaxf(q[r] * 0.015625f - mean[r] * mean[r], 0.f);
        rs[r] = rsqrtf(var + 1e-5f);
    }
    a0 = (a0 - mean) * rs * g0 + b0;
    a1 = (a1 - mean) * rs * g1 + b1;
    a2 = (a2 - mean) * rs * g2 + b2;
    a3 = (a3 - mean) * rs * g3 + b3;
    if (DOGELU) { a0 = gelu4(a0); a1 = gelu4(a1); a2 = gelu4(a2); a3 = gelu4(a3); }
}

template <bool DOGELU>
__device__ __forceinline__ void ln128(float &x0, float &x1, float g0_, float g1_,
                                      float b0_, float b1_) {
    float s = x0 + x1, q = x0 * x0 + x1 * x1;
#pragma unroll
    for (int o = 1; o < 64; o <<= 1) { s += __shfl_xor(s, o, 64); q += __shfl_xor(q, o, 64); }
    float mean = s * (1.f / 128.f);
    float var  = fmaxf(q * (1.f / 128.f) - mean * mean, 0.f);
    float rs   = rsqrtf(var + 1e-5f);
    x0 = (x0 - mean) * rs * g0_ + b0_;
    x1 = (x1 - mean) * rs * g1_ + b1_;
    if (DOGELU) { x0 = geluf(x0); x1 = geluf(x1); }
}

__device__ __forceinline__ void store_c(unsigned short (*xr)[136], int colbase, int L,
                                        v4f a0, v4f a1, v4f a2, v4f a3) {
    const int c = L & 15, g = L >> 4;
#pragma unroll
    for (int r = 0; r < 4; r++) {
        xr[4 * g + r][colbase + c]      = f2bs(a0[r]);
        xr[4 * g + r][colbase + 16 + c] = f2bs(a1[r]);
        xr[4 * g + r][colbase + 32 + c] = f2bs(a2[r]);
        xr[4 * g + r][colbase + 48 + c] = f2bs(a3[r]);
    }
}

__device__ __forceinline__ v8s pack8(v4f lo, v4f hi) {
    v8s r;
    r[0] = (short)f2bs(lo[0]); r[1] = (short)f2bs(lo[1]);
    r[2] = (short)f2bs(lo[2]); r[3] = (short)f2bs(lo[3]);
    r[4] = (short)f2bs(hi[0]); r[5] = (short)f2bs(hi[1]);
    r[6] = (short)f2bs(hi[2]); r[7] = (short)f2bs(hi[3]);
    return r;
}

struct Params {
    const float *node_states, *edge_features;
    const float *ee_w1, *ee_b1, *ee_ln_g, *ee_ln_b, *ee_w2, *ee_b2;
    const float *ts_w1, *ts_b1, *ts_ln_g, *ts_ln_b, *ts_w2, *ts_b2, *ts_w3, *ts_b3;
    const float *mc_w1, *mc_b1, *mc_ln_g, *mc_ln_b, *mc_w2, *mc_b2;
    const float *at_in_w, *at_in_b, *at_out_w, *at_out_b;
    const float *ag_w1, *ag_b1, *ag_ln_g, *ag_ln_b, *ag_w2, *ag_b2;
    const float *gt_w, *gt_b, *nn_ln_g, *nn_ln_b, *mn_ln_g, *mn_ln_b;
    float *ws;
    float *out;
};

// ---- prep: identical to R9 (fold enc, pack B-fragments + fp32 k4 packs) ----
__global__ __launch_bounds__(256) void prep_kernel(Params p) {
    int i = blockIdx.x * 256 + threadIdx.x;
    if (i < F_TOTAL) {
        float v;
        if (i < F_BMC) {
            int o = i - F_BTS;
            float s = p.ts_b1[o];
            for (int e = 0; e < E_; e++) s += p.ee_b2[e] * p.ts_w1[e * M_ + o];
            v = s;
        } else if (i < F_AOP) {
            int o = i - F_BMC;
            float s = p.mc_b1[o];
            for (int e = 0; e < E_; e++) s += p.ee_b2[e] * p.mc_w1[(D_ + e) * M_ + o];
            v = s;
        } else if (i < F_AG1P) {
            int x = i - F_AOP, r = x >> 2, kk = x & 3, k4 = r >> 6, ch = r & 63;
            v = p.at_out_w[(4 * k4 + kk) * M_ + ch];
        } else if (i < F_AG2P) {
            int x = i - F_AG1P, r = x >> 2, kk = x & 3, k4 = r >> 7, ch = r & 127;
            v = p.ag_w1[(4 * k4 + kk) * D_ + ch];
        } else if (i < F_GTP) {
            int x = i - F_AG2P, r = x >> 2, kk = x & 3, k4 = r >> 7, ch = r & 127;
            v = p.ag_w2[(4 * k4 + kk) * D_ + ch];
        } else {
            int x = i - F_GTP, r = x >> 2, kk = x & 3, k4 = r >> 7, ch = r & 127;
            v = p.gt_w[(4 * k4 + kk) * D_ + ch];
        }
        p.ws[i] = v;
        return;
    }
    int hi = i - F_TOTAL;
    if (hi >= H_TOTAL) return;
    unsigned short *wsh = (unsigned short *)(p.ws + F_TOTAL);
    int base, NT;
    const int region =
        (hi < H_WTS) ? 0 : (hi < H_TS2) ? 1 : (hi < H_MC1) ? 2 :
        (hi < H_WMCE) ? 3 : (hi < H_MC2) ? 4 : (hi < H_ATI) ? 5 : 6;
    switch (region) {
        case 0: base = H_EE1;  NT = 4;  break;
        case 1: base = H_WTS;  NT = 4;  break;
        case 2: base = H_TS2;  NT = 2;  break;
        case 3: base = H_MC1;  NT = 4;  break;
        case 4: base = H_WMCE; NT = 4;  break;
        case 5: base = H_MC2;  NT = 4;  break;
        default: base = H_ATI; NT = 12; break;
    }
    int r0 = hi - base;
    int j  = r0 & 7, L = (r0 >> 3) & 63, tk = r0 >> 9;
    int kc = tk / NT, T = tk - kc * NT;
    int c  = L & 15, gg = L >> 4;
    int k  = 32 * kc + 8 * gg + j;
    int n  = 16 * T + c;
    float v = 0.f;
    switch (region) {
        case 0: v = (k < E_) ? p.ee_w1[k * M_ + n] : 0.f; break;
        case 1: { float s = 0.f;
                  for (int e = 0; e < E_; e++) s += p.ee_w2[k * E_ + e] * p.ts_w1[e * M_ + n];
                  v = s; } break;
        case 2: v = p.ts_w2[k * 32 + n]; break;
        case 3: v = p.mc_w1[k * M_ + n]; break;
        case 4: { float s = 0.f;
                  for (int e = 0; e < E_; e++) s += p.ee_w2[k * E_ + e] * p.mc_w1[(D_ + e) * M_ + n];
                  v = s; } break;
        case 5: v = p.mc_w2[k * M_ + n]; break;
        default: v = p.at_in_w[k * 192 + n]; break;
    }
    wsh[hi] = f2bs(v);
}

#define SPL4(NAME, EXPR) v4f NAME; { float _b = (EXPR); NAME = (v4f){_b, _b, _b, _b}; }

// two tasks per wave (A=2i, B=2i+1): every stage runs both tasks back-to-back in
// one barrier-free region (independent chains -> scheduler interleaves, shared
// weight/B-frag/LN-param loads). Per-wave LDS doubled: xp[w][task].
__global__ __launch_bounds__(256) void petri_kernel(Params p) {
    const int tid = threadIdx.x;
    const int w   = tid >> 6;
    const int L   = tid & 63;
    const int c   = L & 15, g = L >> 4;
    const int taskA = blockIdx.x * 8 + w * 2;
    const int taskB = taskA + 1;
    const int bsA = taskA / N_, tA = taskA - bsA * N_;
    const int bsB = taskB / N_, tB = taskB - bsB * N_;
    const int mrow = (c < N_) ? c : 0;

    __shared__ unsigned short xp[4][2][16][136];
    __shared__ float xv[4][2][256];

    const float *ws = p.ws;
    const v8s *wb = (const v8s *)((const unsigned short *)(ws + F_TOTAL));
    const v8s zf = {0, 0, 0, 0, 0, 0, 0, 0};

    // =========== E1 (A,B) ===========
    v8s ahA0, ahA1, ahB0, ahB1;
    {
        v8s aA, aB;
        {
            const float *eA = p.edge_features + (((size_t)bsA * N_ + mrow) * N_ + tA) * E_;
            const float *eB = p.edge_features + (((size_t)bsB * N_ + mrow) * N_ + tB) * E_;
            v2f fa = ((const v2f *)eA)[0], fb = ((const v2f *)eA)[1], fc = ((const v2f *)eA)[2];
            v2f ga_ = ((const v2f *)eB)[0], gb = ((const v2f *)eB)[1], gc = ((const v2f *)eB)[2];
            v8s ta = zf, tb = zf;
            ta[0] = (short)f2bs(fa.x); ta[1] = (short)f2bs(fa.y);
            ta[2] = (short)f2bs(fb.x); ta[3] = (short)f2bs(fb.y);
            ta[4] = (short)f2bs(fc.x); ta[5] = (short)f2bs(fc.y);
            tb[0] = (short)f2bs(ga_.x); tb[1] = (short)f2bs(ga_.y);
            tb[2] = (short)f2bs(gb.x); tb[3] = (short)f2bs(gb.y);
            tb[4] = (short)f2bs(gc.x); tb[5] = (short)f2bs(gc.y);
            aA = (g == 0) ? ta : zf;
            aB = (g == 0) ? tb : zf;
        }
        float b0 = p.ee_b1[c], b1 = p.ee_b1[16 + c], b2 = p.ee_b1[32 + c], b3 = p.ee_b1[48 + c];
        v4f h0A = {b0, b0, b0, b0}, h1A = {b1, b1, b1, b1}, h2A = {b2, b2, b2, b2}, h3A = {b3, b3, b3, b3};
        v4f h0B = h0A, h1B = h1A, h2B = h2A, h3B = h3A;
        {
            v8s W0 = wb[0 * 64 + L], W1 = wb[1 * 64 + L], W2 = wb[2 * 64 + L], W3 = wb[3 * 64 + L];
            h0A = MFMA16(aA, W0, h0A); h0B = MFMA16(aB, W0, h0B);
            h1A = MFMA16(aA, W1, h1A); h1B = MFMA16(aB, W1, h1B);
            h2A = MFMA16(aA, W2, h2A); h2B = MFMA16(aB, W2, h2B);
            h3A = MFMA16(aA, W3, h3A); h3B = MFMA16(aB, W3, h3B);
        }
        float lg0 = p.ee_ln_g[c], lg1 = p.ee_ln_g[16 + c], lg2 = p.ee_ln_g[32 + c], lg3 = p.ee_ln_g[48 + c];
        float lb0 = p.ee_ln_b[c], lb1 = p.ee_ln_b[16 + c], lb2 = p.ee_ln_b[32 + c], lb3 = p.ee_ln_b[48 + c];
        ln_c64<true>(h0A, h1A, h2A, h3A, lg0, lg1, lg2, lg3, lb0, lb1, lb2, lb3);
        ln_c64<true>(h0B, h1B, h2B, h3B, lg0, lg1, lg2, lg3, lb0, lb1, lb2, lb3);
        store_c(xp[w][0], 64, L, h0A, h1A, h2A, h3A);
        store_c(xp[w][1], 64, L, h0B, h1B, h2B, h3B);
        LDS_ORDER();
        ahA0 = *(const v8s *)&xp[w][0][c][64 + 8 * g];
        ahA1 = *(const v8s *)&xp[w][0][c][96 + 8 * g];
        ahB0 = *(const v8s *)&xp[w][1][c][64 + 8 * g];
        ahB1 = *(const v8s *)&xp[w][1][c][96 + 8 * g];
    }

    // =========== TS1 + TS2/3 (A,B) ===========
    v4f tsvA, tsvB;
    {
        float b0 = ws[F_BTS + c], b1 = ws[F_BTS + 16 + c], b2 = ws[F_BTS + 32 + c], b3 = ws[F_BTS + 48 + c];
        v4f t0A = {b0, b0, b0, b0}, t1A = {b1, b1, b1, b1}, t2A = {b2, b2, b2, b2}, t3A = {b3, b3, b3, b3};
        v4f t0B = t0A, t1B = t1A, t2B = t2A, t3B = t3A;
        {
            v8s W;
            W = wb[256 + 0 * 64 + L]; t0A = MFMA16(ahA0, W, t0A); t0B = MFMA16(ahB0, W, t0B);
            W = wb[256 + 4 * 64 + L]; t0A = MFMA16(ahA1, W, t0A); t0B = MFMA16(ahB1, W, t0B);
            W = wb[256 + 1 * 64 + L]; t1A = MFMA16(ahA0, W, t1A); t1B = MFMA16(ahB0, W, t1B);
            W = wb[256 + 5 * 64 + L]; t1A = MFMA16(ahA1, W, t1A); t1B = MFMA16(ahB1, W, t1B);
            W = wb[256 + 2 * 64 + L]; t2A = MFMA16(ahA0, W, t2A); t2B = MFMA16(ahB0, W, t2B);
            W = wb[256 + 6 * 64 + L]; t2A = MFMA16(ahA1, W, t2A); t2B = MFMA16(ahB1, W, t2B);
            W = wb[256 + 3 * 64 + L]; t3A = MFMA16(ahA0, W, t3A); t3B = MFMA16(ahB0, W, t3B);
            W = wb[256 + 7 * 64 + L]; t3A = MFMA16(ahA1, W, t3A); t3B = MFMA16(ahB1, W, t3B);
        }
        float lg0 = p.ts_ln_g[c], lg1 = p.ts_ln_g[16 + c], lg2 = p.ts_ln_g[32 + c], lg3 = p.ts_ln_g[48 + c];
        float lb0 = p.ts_ln_b[c], lb1 = p.ts_ln_b[16 + c], lb2 = p.ts_ln_b[32 + c], lb3 = p.ts_ln_b[48 + c];
        ln_c64<true>(t0A, t1A, t2A, t3A, lg0, lg1, lg2, lg3, lb0, lb1, lb2, lb3);
        ln_c64<true>(t0B, t1B, t2B, t3B, lg0, lg1, lg2, lg3, lb0, lb1, lb2, lb3);
        store_c(xp[w][0], 0, L, t0A, t1A, t2A, t3A);
        store_c(xp[w][1], 0, L, t0B, t1B, t2B, t3B);
        LDS_ORDER();
        v8s atA0 = *(const v8s *)&xp[w][0][c][0 + 8 * g];
        v8s atA1 = *(const v8s *)&xp[w][0][c][32 + 8 * g];
        v8s atB0 = *(const v8s *)&xp[w][1][c][0 + 8 * g];
        v8s atB1 = *(const v8s *)&xp[w][1][c][32 + 8 * g];
        float u0b = p.ts_b2[c], u1b = p.ts_b2[16 + c];
        v4f u0A = {u0b, u0b, u0b, u0b}, u1A = {u1b, u1b, u1b, u1b};
        v4f u0B = u0A, u1B = u1A;
        {
            v8s W;
            W = wb[768 + 0 * 64 + L]; u0A = MFMA16(atA0, W, u0A); u0B = MFMA16(atB0, W, u0B);
            W = wb[768 + 2 * 64 + L]; u0A = MFMA16(atA1, W, u0A); u0B = MFMA16(atB1, W, u0B);
            W = wb[768 + 1 * 64 + L]; u1A = MFMA16(atA0, W, u1A); u1B = MFMA16(atB0, W, u1B);
            W = wb[768 + 3 * 64 + L]; u1A = MFMA16(atA1, W, u1A); u1B = MFMA16(atB1, W, u1B);
        }
        float w3a = p.ts_w3[c], w3b = p.ts_w3[16 + c], b3v = p.ts_b3[0];
        v4f dA = gelu4(u0A) * w3a + gelu4(u1A) * w3b;
        v4f dB = gelu4(u0B) * w3a + gelu4(u1B) * w3b;
#pragma unroll
        for (int o = 1; o < 16; o <<= 1)
#pragma unroll
            for (int r = 0; r < 4; r++) {
                dA[r] += __shfl_xor(dA[r], o, 64);
                dB[r] += __shfl_xor(dB[r], o, 64);
            }
#pragma unroll
        for (int r = 0; r < 4; r++) {
            tsvA[r] = sigm(dA[r] + b3v);
            tsvB[r] = sigm(dB[r] + b3v);
        }
    }

    // =========== MC1 (A,B) ===========
    v8s amA0, amA1, amB0, amB1;
    {
        float b0 = ws[F_BMC + c], b1 = ws[F_BMC + 16 + c], b2 = ws[F_BMC + 32 + c], b3 = ws[F_BMC + 48 + c];
        v4f m0A = {b0, b0, b0, b0}, m1A = {b1, b1, b1, b1}, m2A = {b2, b2, b2, b2}, m3A = {b3, b3, b3, b3};
        v4f m0B = m0A, m1B = m1A, m2B = m2A, m3B = m3A;
        const float *nsrA = p.node_states + ((size_t)bsA * N_ + mrow) * D_;
        const float *nsrB = p.node_states + ((size_t)bsB * N_ + mrow) * D_;
#pragma unroll
        for (int kc = 0; kc < 4; kc++) {
            v8s anA = pack8(*(const v4f *)(nsrA + 32 * kc + 8 * g),
                            *(const v4f *)(nsrA + 32 * kc + 8 * g + 4));
            v8s anB = pack8(*(const v4f *)(nsrB + 32 * kc + 8 * g),
                            *(const v4f *)(nsrB + 32 * kc + 8 * g + 4));
            v8s W;
            W = wb[1024 + (kc * 4 + 0) * 64 + L]; m0A = MFMA16(anA, W, m0A); m0B = MFMA16(anB, W, m0B);
            W = wb[1024 + (kc * 4 + 1) * 64 + L]; m1A = MFMA16(anA, W, m1A); m1B = MFMA16(anB, W, m1B);
            W = wb[1024 + (kc * 4 + 2) * 64 + L]; m2A = MFMA16(anA, W, m2A); m2B = MFMA16(anB, W, m2B);
            W = wb[1024 + (kc * 4 + 3) * 64 + L]; m3A = MFMA16(anA, W, m3A); m3B = MFMA16(anB, W, m3B);
        }
        {
            v8s W;
            W = wb[2048 + 0 * 64 + L]; m0A = MFMA16(ahA0, W, m0A); m0B = MFMA16(ahB0, W, m0B);
            W = wb[2048 + 4 * 64 + L]; m0A = MFMA16(ahA1, W, m0A); m0B = MFMA16(ahB1, W, m0B);
            W = wb[2048 + 1 * 64 + L]; m1A = MFMA16(ahA0, W, m1A); m1B = MFMA16(ahB0, W, m1B);
            W = wb[2048 + 5 * 64 + L]; m1A = MFMA16(ahA1, W, m1A); m1B = MFMA16(ahB1, W, m1B);
            W = wb[2048 + 2 * 64 + L]; m2A = MFMA16(ahA0, W, m2A); m2B = MFMA16(ahB0, W, m2B);
            W = wb[2048 + 6 * 64 + L]; m2A = MFMA16(ahA1, W, m2A); m2B = MFMA16(ahB1, W, m2B);
            W = wb[2048 + 3 * 64 + L]; m3A = MFMA16(ahA0, W, m3A); m3B = MFMA16(ahB0, W, m3B);
            W = wb[2048 + 7 * 64 + L]; m3A = MFMA16(ahA1, W, m3A); m3B = MFMA16(ahB1, W, m3B);
        }
        float lg0 = p.mc_ln_g[c], lg1 = p.mc_ln_g[16 + c], lg2 = p.mc_ln_g[32 + c], lg3 = p.mc_ln_g[48 + c];
        float lb0 = p.mc_ln_b[c], lb1 = p.mc_ln_b[16 + c], lb2 = p.mc_ln_b[32 + c], lb3 = p.mc_ln_b[48 + c];
        ln_c64<true>(m0A, m1A, m2A, m3A, lg0, lg1, lg2, lg3, lb0, lb1, lb2, lb3);
        ln_c64<true>(m0B, m1B, m2B, m3B, lg0, lg1, lg2, lg3, lb0, lb1, lb2, lb3);
        store_c(xp[w][0], 0, L, m0A, m1A, m2A, m3A);
        store_c(xp[w][1], 0, L, m0B, m1B, m2B, m3B);
        LDS_ORDER();
        amA0 = *(const v8s *)&xp[w][0][c][0 + 8 * g];
        amA1 = *(const v8s *)&xp[w][0][c][32 + 8 * g];
        amB0 = *(const v8s *)&xp[w][1][c][0 + 8 * g];
        amB1 = *(const v8s *)&xp[w][1][c][32 + 8 * g];
    }

    // =========== MC2 (A,B) ===========
    v8s awA0, awA1, awB0, awB1;
    {
        float b0 = p.mc_b2[c], b1 = p.mc_b2[16 + c], b2 = p.mc_b2[32 + c], b3 = p.mc_b2[48 + c];
        v4f x0A = {b0, b0, b0, b0}, x1A = {b1, b1, b1, b1}, x2A = {b2, b2, b2, b2}, x3A = {b3, b3, b3, b3};
        v4f x0B = x0A, x1B = x1A, x2B = x2A, x3B = x3A;
        {
            v8s W;
            W = wb[2560 + 0 * 64 + L]; x0A = MFMA16(amA0, W, x0A); x0B = MFMA16(amB0, W, x0B);
            W = wb[2560 + 4 * 64 + L]; x0A = MFMA16(amA1, W, x0A); x0B = MFMA16(amB1, W, x0B);
            W = wb[2560 + 1 * 64 + L]; x1A = MFMA16(amA0, W, x1A); x1B = MFMA16(amB0, W, x1B);
            W = wb[2560 + 5 * 64 + L]; x1A = MFMA16(amA1, W, x1A); x1B = MFMA16(amB1, W, x1B);
            W = wb[2560 + 2 * 64 + L]; x2A = MFMA16(amA0, W, x2A); x2B = MFMA16(amB0, W, x2B);
            W = wb[2560 + 6 * 64 + L]; x2A = MFMA16(amA1, W, x2A); x2B = MFMA16(amB1, W, x2B);
            W = wb[2560 + 3 * 64 + L]; x3A = MFMA16(amA0, W, x3A); x3B = MFMA16(amB0, W, x3B);
            W = wb[2560 + 7 * 64 + L]; x3A = MFMA16(amA1, W, x3A); x3B = MFMA16(amB1, W, x3B);
        }
        x0A *= tsvA; x1A *= tsvA; x2A *= tsvA; x3A *= tsvA;
        x0B *= tsvB; x1B *= tsvB; x2B *= tsvB; x3B *= tsvB;
        float lg0 = p.mn_ln_g[c], lg1 = p.mn_ln_g[16 + c], lg2 = p.mn_ln_g[32 + c], lg3 = p.mn_ln_g[48 + c];
        float lb0 = p.mn_ln_b[c], lb1 = p.mn_ln_b[16 + c], lb2 = p.mn_ln_b[32 + c], lb3 = p.mn_ln_b[48 + c];
        ln_c64<false>(x0A, x1A, x2A, x3A, lg0, lg1, lg2, lg3, lb0, lb1, lb2, lb3);
        ln_c64<false>(x0B, x1B, x2B, x3B, lg0, lg1, lg2, lg3, lb0, lb1, lb2, lb3);
        store_c(xp[w][0], 0, L, x0A, x1A, x2A, x3A);
        store_c(xp[w][1], 0, L, x0B, x1B, x2B, x3B);
        LDS_ORDER();
        awA0 = *(const v8s *)&xp[w][0][c][0 + 8 * g];
        awA1 = *(const v8s *)&xp[w][0][c][32 + 8 * g];
        awB0 = *(const v8s *)&xp[w][1][c][0 + 8 * g];
        awB1 = *(const v8s *)&xp[w][1][c][32 + 8 * g];
    }

    // =========== AT: Q,K stored per-tile; V kept in regs ===========
    v4f vtA0, vtA1, vtA2, vtA3, vtB0, vtB1, vtB2, vtB3;
    {
#define AT_QK(T, DSTC)                                                          \
        { float _b = p.at_in_b[16 * (T) + c];                                    \
          v8s W0 = wb[3072 + (T) * 64 + L], W1 = wb[3072 + (12 + (T)) * 64 + L]; \
          v4f aA = {_b, _b, _b, _b}, aB = aA;                                    \
          aA = MFMA16(awA0, W0, aA); aA = MFMA16(awA1, W1, aA);                  \
          aB = MFMA16(awB0, W0, aB); aB = MFMA16(awB1, W1, aB);                  \
          _Pragma("unroll")                                                      \
          for (int r = 0; r < 4; r++) {                                          \
              xp[w][0][4 * g + r][(DSTC) + c] = f2bs(aA[r]);                     \
              xp[w][1][4 * g + r][(DSTC) + c] = f2bs(aB[r]);                     \
          } }
        AT_QK(0, 0)  AT_QK(1, 16)  AT_QK(2, 32)  AT_QK(3, 48)
        AT_QK(4, 64) AT_QK(5, 80)  AT_QK(6, 96)  AT_QK(7, 112)
#undef AT_QK
#define AT_V(T, VA, VB)                                                          \
        { float _b = p.at_in_b[16 * (T) + c];                                    \
          v8s W0 = wb[3072 + (T) * 64 + L], W1 = wb[3072 + (12 + (T)) * 64 + L]; \
          VA = (v4f){_b, _b, _b, _b}; VB = VA;                                   \
          VA = MFMA16(awA0, W0, VA); VA = MFMA16(awA1, W1, VA);                  \
          VB = MFMA16(awB0, W0, VB); VB = MFMA16(awB1, W1, VB); }
        AT_V(8, vtA0, vtB0) AT_V(9, vtA1, vtB1) AT_V(10, vtA2, vtB2) AT_V(11, vtA3, vtB3)
#undef AT_V
        LDS_ORDER();
    }

    // =========== attention (A,B) ===========
    float agA0, agA1, agA2, agA3, agB0, agB1, agB2, agB3;
#define ATTN(TI, VT0, VT1, VT2, VT3, O0, O1, O2, O3)                              \
    {                                                                             \
        const v4f z4 = {0.f, 0.f, 0.f, 0.f};                                      \
        v4f s0, s1, s2, s3;                                                       \
        {                                                                         \
            v8s aq, bk;                                                           \
            aq = (g < 2) ? *(const v8s *)&xp[w][TI][c][0 + 8 * g] : zf;           \
            bk = (g < 2) ? *(const v8s *)&xp[w][TI][c][64 + 0 + 8 * g] : zf;      \
            s0 = MFMA16(aq, bk, z4);                                              \
            aq = (g < 2) ? *(const v8s *)&xp[w][TI][c][16 + 8 * g] : zf;          \
            bk = (g < 2) ? *(const v8s *)&xp[w][TI][c][64 + 16 + 8 * g] : zf;     \
            s1 = MFMA16(aq, bk, z4);                                              \
            aq = (g < 2) ? *(const v8s *)&xp[w][TI][c][32 + 8 * g] : zf;          \
            bk = (g < 2) ? *(const v8s *)&xp[w][TI][c][64 + 32 + 8 * g] : zf;     \
            s2 = MFMA16(aq, bk, z4);                                              \
            aq = (g < 2) ? *(const v8s *)&xp[w][TI][c][48 + 8 * g] : zf;          \
            bk = (g < 2) ? *(const v8s *)&xp[w][TI][c][64 + 48 + 8 * g] : zf;     \
            s3 = MFMA16(aq, bk, z4);                                              \
        }                                                                         \
        if (c >= N_) {                                                            \
            v4f neg = {-1e30f, -1e30f, -1e30f, -1e30f};                           \
            s0 = neg; s1 = neg; s2 = neg; s3 = neg;                               \
        }                                                                         \
        v4f m0 = s0, m1 = s1, m2 = s2, m3 = s3;                                   \
        _Pragma("unroll")                                                         \
        for (int o = 1; o < 16; o <<= 1)                                          \
            _Pragma("unroll")                                                     \
            for (int r = 0; r < 4; r++) {                                         \
                m0[r] = fmaxf(m0[r], __shfl_xor(m0[r], o, 64));                   \
                m1[r] = fmaxf(m1[r], __shfl_xor(m1[r], o, 64));                   \
                m2[r] = fmaxf(m2[r], __shfl_xor(m2[r], o, 64));                   \
                m3[r] = fmaxf(m3[r], __shfl_xor(m3[r], o, 64));                   \
            }                                                                     \
        v4f e0, e1, e2, e3;                                                       \
        _Pragma("unroll")                                                         \
        for (int r = 0; r < 4; r++) {                                             \
            e0[r] = __expf((s0[r] - m0[r]) * 0.25f);                              \
            e1[r] = __expf((s1[r] - m1[r]) * 0.25f);                              \
            e2[r] = __expf((s2[r] - m2[r]) * 0.25f);                              \
            e3[r] = __expf((s3[r] - m3[r]) * 0.25f);                              \
        }                                                                         \
        v4f z0 = e0, z1 = e1, z2 = e2, z3 = e3;                                   \
        _Pragma("unroll")                                                         \
        for (int o = 1; o < 16; o <<= 1)                                          \
            _Pragma("unroll")                                                     \
            for (int r = 0; r < 4; r++) {                                         \
                z0[r] += __shfl_xor(z0[r], o, 64);                                \
                z1[r] += __shfl_xor(z1[r], o, 64);                                \
                z2[r] += __shfl_xor(z2[r], o, 64);                                \
                z3[r] += __shfl_xor(z3[r], o, 64);                                \
            }                                                                     \
        _Pragma("unroll")                                                         \
        for (int r = 0; r < 4; r++) {                                             \
            e0[r] *= __builtin_amdgcn_rcpf(z0[r]);                                \
            e1[r] *= __builtin_amdgcn_rcpf(z1[r]);                                \
            e2[r] *= __builtin_amdgcn_rcpf(z2[r]);                                \
            e3[r] *= __builtin_amdgcn_rcpf(z3[r]);                                \
        }                                                                         \
        int row0 = 4 * g;                                                         \
        float cs0 = e0[0], cs1 = e1[0], cs2 = e2[0], cs3 = e3[0];                 \
        _Pragma("unroll")                                                         \
        for (int r = 1; r < 4; r++) {                                             \
            bool ok = (row0 + r) < N_;                                            \
            cs0 += ok ? e0[r] : 0.f; cs1 += ok ? e1[r] : 0.f;                     \
            cs2 += ok ? e2[r] : 0.f; cs3 += ok ? e3[r] : 0.f;                     \
        }                                                                         \
        cs0 += __shfl_xor(cs0, 16, 64); cs0 += __shfl_xor(cs0, 32, 64);           \
        cs1 += __shfl_xor(cs1, 16, 64); cs1 += __shfl_xor(cs1, 32, 64);           \
        cs2 += __shfl_xor(cs2, 16, 64); cs2 += __shfl_xor(cs2, 32, 64);           \
        cs3 += __shfl_xor(cs3, 16, 64); cs3 += __shfl_xor(cs3, 32, 64);           \
        int pbase = (((L & 48) + ((L & 48) >> 2)) << 2);                          \
        O0 = 0.f; O1 = 0.f; O2 = 0.f; O3 = 0.f;                                   \
        _Pragma("unroll")                                                         \
        for (int r = 0; r < 4; r++) {                                             \
            int pa = pbase + 4 * r;                                               \
            float c0 = __int_as_float(__builtin_amdgcn_ds_bpermute(pa, __float_as_int(cs0))); \
            float c1 = __int_as_float(__builtin_amdgcn_ds_bpermute(pa, __float_as_int(cs1))); \
            float c2 = __int_as_float(__builtin_amdgcn_ds_bpermute(pa, __float_as_int(cs2))); \
            float c3 = __int_as_float(__builtin_amdgcn_ds_bpermute(pa, __float_as_int(cs3))); \
            O0 += c0 * VT0[r]; O1 += c1 * VT1[r];                                 \
            O2 += c2 * VT2[r]; O3 += c3 * VT3[r];                                 \
        }                                                                         \
        O0 += __shfl_xor(O0, 16, 64); O0 += __shfl_xor(O0, 32, 64);               \
        O1 += __shfl_xor(O1, 16, 64); O1 += __shfl_xor(O1, 32, 64);               \
        O2 += __shfl_xor(O2, 16, 64); O2 += __shfl_xor(O2, 32, 64);               \
        O3 += __shfl_xor(O3, 16, 64); O3 += __shfl_xor(O3, 32, 64);               \
        const float inv13 = 1.0f / 13.0f;                                         \
        O0 *= inv13; O1 *= inv13; O2 *= inv13; O3 *= inv13;                       \
    }
    ATTN(0, vtA0, vtA1, vtA2, vtA3, agA0, agA1, agA2, agA3)
    ATTN(1, vtB0, vtB1, vtB2, vtB3, agB0, agB1, agB2, agB3)
#undef ATTN

    // =========== node phase (A,B joint, shared weight loads) ===========
    if (g == 0) {
        xv[w][0][c] = agA0; xv[w][0][16 + c] = agA1; xv[w][0][32 + c] = agA2; xv[w][0][48 + c] = agA3;
        xv[w][1][c] = agB0; xv[w][1][16 + c] = agB1; xv[w][1][32 + c] = agB2; xv[w][1][48 + c] = agB3;
    }
    LDS_ORDER();
    {   // at_out
        const v4f *AO = (const v4f *)(ws + F_AOP);
        v2f spA = mkpair(p.at_out_b[L], 0.f), spB = spA;
#pragma unroll 4
        for (int k4 = 0; k4 < 16; k4++) {
            v4f wv = AO[k4 * 64 + L];
            v4f xA = *(const v4f *)&xv[w][0][4 * k4];
            v4f xB = *(const v4f *)&xv[w][1][4 * k4];
            spA = PKFMA(LO2(xA), LO2(wv), PKFMA(HI2(xA), HI2(wv), spA));
            spB = PKFMA(LO2(xB), LO2(wv), PKFMA(HI2(xB), HI2(wv), spB));
        }
        xv[w][0][64 + L] = spA.x + spA.y;
        xv[w][1][64 + L] = spB.x + spB.y;
    }
    LDS_ORDER();
    {   // ag1 -> LN -> gelu
        const v4f *AG = (const v4f *)(ws + F_AG1P);
        float bb0 = p.ag_b1[L], bb1 = p.ag_b1[L + 64];
        v2f pA0 = mkpair(bb0, 0.f), pA1 = mkpair(bb1, 0.f);
        v2f pB0 = pA0, pB1 = pA1;
#pragma unroll 4
        for (int k4 = 0; k4 < 16; k4++) {
            v4f w0 = AG[k4 * 128 + L], w1 = AG[k4 * 128 + 64 + L];
            v4f xA = *(const v4f *)&xv[w][0][64 + 4 * k4];
            v4f xB = *(const v4f *)&xv[w][1][64 + 4 * k4];
            pA0 = PKFMA(LO2(xA), LO2(w0), PKFMA(HI2(xA), HI2(w0), pA0));
            pA1 = PKFMA(LO2(xA), LO2(w1), PKFMA(HI2(xA), HI2(w1), pA1));
            pB0 = PKFMA(LO2(xB), LO2(w0), PKFMA(HI2(xB), HI2(w0), pB0));
            pB1 = PKFMA(LO2(xB), LO2(w1), PKFMA(HI2(xB), HI2(w1), pB1));
        }
        float aA0 = pA0.x + pA0.y, aA1 = pA1.x + pA1.y;
        float aB0 = pB0.x + pB0.y, aB1 = pB1.x + pB1.y;
        float lg0 = p.ag_ln_g[L], lg1 = p.ag_ln_g[L + 64];
        float lb0 = p.ag_ln_b[L], lb1 = p.ag_ln_b[L + 64];
        ln128<true>(aA0, aA1, lg0, lg1, lb0, lb1);
        ln128<true>(aB0, aB1, lg0, lg1, lb0, lb1);
        xv[w][0][128 + L] = aA0; xv[w][0][192 + L] = aA1;
        xv[w][1][128 + L] = aB0; xv[w][1][192 + L] = aB1;
    }
    LDS_ORDER();
    float nivA0, nivA1, nivB0, nivB1;
    {   // ag2
        const v4f *AG = (const v4f *)(ws + F_AG2P);
        float bb0 = p.ag_b2[L], bb1 = p.ag_b2[L + 64];
        v2f pA0 = mkpair(bb0, 0.f), pA1 = mkpair(bb1, 0.f);
        v2f pB0 = pA0, pB1 = pA1;
#pragma unroll 8
        for (int k4 = 0; k4 < 32; k4++) {
            v4f w0 = AG[k4 * 128 + L], w1 = AG[k4 * 128 + 64 + L];
            v4f xA = *(const v4f *)&xv[w][0][128 + 4 * k4];
            v4f xB = *(const v4f *)&xv[w][1][128 + 4 * k4];
            pA0 = PKFMA(LO2(xA), LO2(w0), PKFMA(HI2(xA), HI2(w0), pA0));
            pA1 = PKFMA(LO2(xA), LO2(w1), PKFMA(HI2(xA), HI2(w1), pA1));
            pB0 = PKFMA(LO2(xB), LO2(w0), PKFMA(HI2(xB), HI2(w0), pB0));
            pB1 = PKFMA(LO2(xB), LO2(w1), PKFMA(HI2(xB), HI2(w1), pB1));
        }
        nivA0 = pA0.x + pA0.y; nivA1 = pA1.x + pA1.y;
        nivB0 = pB0.x + pB0.y; nivB1 = pB1.x + pB1.y;
    }
    // stage gate input [ns_t | nil] per task
    const float *nstA = p.node_states + ((size_t)bsA * N_ + tA) * D_;
    const float *nstB = p.node_states + ((size_t)bsB * N_ + tB) * D_;
    float nA0 = nstA[L], nA1 = nstA[L + 64];
    float nB0 = nstB[L], nB1 = nstB[L + 64];
    xv[w][0][L] = nA0; xv[w][0][64 + L] = nA1;
    xv[w][0][128 + L] = nivA0; xv[w][0][192 + L] = nivA1;
    xv[w][1][L] = nB0; xv[w][1][64 + L] = nB1;
    xv[w][1][128 + L] = nivB0; xv[w][1][192 + L] = nivB1;
    LDS_ORDER();
    float updA0, updA1, updB0, updB1;
    {   // gate GEMV K=256
        const v4f *GT = (const v4f *)(ws + F_GTP);
        float bb0 = p.gt_b[L], bb1 = p.gt_b[L + 64];
        v2f pA0 = mkpair(bb0, 0.f), pA1 = mkpair(bb1, 0.f);
        v2f pB0 = pA0, pB1 = pA1;
#pragma unroll 8
        for (int k4 = 0; k4 < 64; k4++) {
            v4f w0 = GT[k4 * 128 + L], w1 = GT[k4 * 128 + 64 + L];
            v4f xA = *(const v4f *)&xv[w][0][4 * k4];
            v4f xB = *(const v4f *)&xv[w][1][4 * k4];
            pA0 = PKFMA(LO2(xA), LO2(w0), PKFMA(HI2(xA), HI2(w0), pA0));
            pA1 = PKFMA(LO2(xA), LO2(w1), PKFMA(HI2(xA), HI2(w1), pA1));
            pB0 = PKFMA(LO2(xB), LO2(w0), PKFMA(HI2(xB), HI2(w0), pB0));
            pB1 = PKFMA(LO2(xB), LO2(w1), PKFMA(HI2(xB), HI2(w1), pB1));
        }
        float gA0 = sigm(pA0.x + pA0.y), gA1 = sigm(pA1.x + pA1.y);
        float gB0 = sigm(pB0.x + pB0.y), gB1 = sigm(pB1.x + pB1.y);
        updA0 = gA0 * nivA0 + (1.f - gA0) * nA0;
        updA1 = gA1 * nivA1 + (1.f - gA1) * nA1;
        updB0 = gB0 * nivB0 + (1.f - gB0) * nB0;
        updB1 = gB1 * nivB1 + (1.f - gB1) * nB1;
    }
    {
        float lg0 = p.nn_ln_g[L], lg1 = p.nn_ln_g[L + 64];
        float lb0 = p.nn_ln_b[L], lb1 = p.nn_ln_b[L + 64];
        ln128<false>(updA0, updA1, lg0, lg1, lb0, lb1);
        ln128<false>(updB0, updB1, lg0, lg1, lb0, lb1);
        float *opA = p.out + ((size_t)bsA * N_ + tA) * D_;
        float *opB = p.out + ((size_t)bsB * N_ + tB) * D_;
        opA[L] = updA0; opA[L + 64] = updA1;
        opB[L] = updB0; opB[L + 64] = updB1;
    }
}

extern "C" void kernel_launch(void* const* d_in, const int* in_sizes, int n_in,
                              void* d_out, int out_size, void* d_ws, size_t ws_size,
                              hipStream_t stream) {
    Params p;
    p.node_states   = (const float*)d_in[0];
    p.edge_features = (const float*)d_in[1];
    p.ee_w1   = (const float*)d_in[2];
    p.ee_b1   = (const float*)d_in[3];
    p.ee_ln_g = (const float*)d_in[4];
    p.ee_ln_b = (const float*)d_in[5];
    p.ee_w2   = (const float*)d_in[6];
    p.ee_b2   = (const float*)d_in[7];
    p.ts_w1   = (const float*)d_in[8];
    p.ts_b1   = (const float*)d_in[9];
    p.ts_ln_g = (const float*)d_in[10];
    p.ts_ln_b = (const float*)d_in[11];
    p.ts_w2   = (const float*)d_in[12];
    p.ts_b2   = (const float*)d_in[13];
    p.ts_w3   = (const float*)d_in[14];
    p.ts_b3   = (const float*)d_in[15];
    p.mc_w1   = (const float*)d_in[16];
    p.mc_b1   = (const float*)d_in[17];
    p.mc_ln_g = (const float*)d_in[18];
    p.mc_ln_b = (const float*)d_in[19];
    p.mc_w2   = (const float*)d_in[20];
    p.mc_b2   = (const float*)d_in[21];
    p.at_in_w  = (const float*)d_in[22];
    p.at_in_b  = (const float*)d_in[23];
    p.at_out_w = (const float*)d_in[24];
    p.at_out_b = (const float*)d_in[25];
    p.ag_w1   = (const float*)d_in[26];
    p.ag_b1   = (const float*)d_in[27];
    p.ag_ln_g = (const float*)d_in[28];
    p.ag_ln_b = (const float*)d_in[29];
    p.ag_w2   = (const float*)d_in[30];
    p.ag_b2   = (const float*)d_in[31];
    p.gt_w    = (const float*)d_in[32];
    p.gt_b    = (const float*)d_in[33];
    p.nn_ln_g = (const float*)d_in[34];
    p.nn_ln_b = (const float*)d_in[35];
    p.mn_ln_g = (const float*)d_in[36];
    p.mn_ln_b = (const float*)d_in[37];
    p.ws      = (float*)d_ws;
    p.out     = (float*)d_out;

    const int prep_threads = F_TOTAL + H_TOTAL;
    hipLaunchKernelGGL(prep_kernel, dim3((prep_threads + 255) / 256), dim3(256), 0, stream, p);
    hipLaunchKernelGGL(petri_kernel, dim3((B_ * S_ * N_) / 8), dim3(256), 0, stream, p);
}

// Round 11
// 387.204 us; speedup vs baseline: 2.7806x; 1.1225x over previous
//
#include <hip/hip_runtime.h>

#define B_  16
#define S_  128
#define N_  13
#define D_  128
#define E_  6
#define M_  64
#define H_  4

typedef float v2f __attribute__((ext_vector_type(2)));
typedef float v4f __attribute__((ext_vector_type(4)));
typedef short v8s __attribute__((ext_vector_type(8)));

#define MFMA16(A, B, C) __builtin_amdgcn_mfma_f32_16x16x32_bf16((A), (B), (C), 0, 0, 0)
#define LDS_ORDER() __asm__ __volatile__("" ::: "memory")

#if __has_builtin(__builtin_elementwise_fma)
#define PKFMA(A, B, C) __builtin_elementwise_fma((A), (B), (C))
#else
#define PKFMA(A, B, C) ((A) * (B) + (C))
#endif
#define LO2(X) __builtin_shufflevector((X), (X), 0, 1)
#define HI2(X) __builtin_shufflevector((X), (X), 2, 3)

// ---- workspace layout ----
#define F_BTS   0
#define F_BMC   64
#define F_AOP   128
#define F_AG1P  4224
#define F_AG2P  12416
#define F_GTP   28800
#define F_TOTAL 61568
#define H_EE1   0
#define H_WTS   2048
#define H_TS2   6144
#define H_MC1   8192
#define H_WMCE  16384
#define H_MC2   20480
#define H_ATI   24576
#define H_TOTAL 36864

__device__ __forceinline__ v2f mkpair(float a, float b) { v2f r; r.x = a; r.y = b; return r; }

__device__ __forceinline__ unsigned short f2bs(float x) {  // RTNE fp32->bf16
    unsigned u = __float_as_uint(x);
    u += 0x7FFFu + ((u >> 16) & 1u);
    return (unsigned short)(u >> 16);
}
__device__ __forceinline__ float erf_fast(float x) {  // A&S 7.1.26, |eps|<1.5e-7
    float ax = fabsf(x);
    float t  = __builtin_amdgcn_rcpf(fmaf(0.3275911f, ax, 1.0f));
    float p  = t * fmaf(t, fmaf(t, fmaf(t, fmaf(t, 1.061405429f, -1.453152027f),
                                        1.421413741f), -0.284496736f), 0.254829592f);
    float r  = fmaf(-p, __expf(-ax * ax), 1.0f);
    return copysignf(r, x);
}
__device__ __forceinline__ float geluf(float x) {
    return 0.5f * x * (1.0f + erf_fast(x * 0.7071067811865475f));
}
__device__ __forceinline__ float sigm(float x) { return 1.0f / (1.0f + __expf(-x)); }
__device__ __forceinline__ v4f gelu4(v4f x) {
    v4f r; r[0] = geluf(x[0]); r[1] = geluf(x[1]); r[2] = geluf(x[2]); r[3] = geluf(x[3]);
    return r;
}

template <bool DOGELU>
__device__ __forceinline__ void ln_c64(v4f &a0, v4f &a1, v4f &a2, v4f &a3,
                                       float g0, float g1, float g2, float g3,
                                       float b0, float b1, float b2, float b3) {
    v4f s = a0 + a1 + a2 + a3;
    v4f q = a0 * a0 + a1 * a1 + a2 * a2 + a3 * a3;
#pragma unroll
    for (int o = 1; o < 16; o <<= 1) {
#pragma unroll
        for (int r = 0; r < 4; r++) {
            s[r] += __shfl_xor(s[r], o, 64);
            q[r] += __shfl_xor(q[r], o, 64);
        }
    }
    v4f mean = s * 0.015625f;
    v4f rs;
#pragma unroll
    for (int r = 0; r < 4; r++) {
        float var = fmaxf(q[r] * 0.015625f - mean[r] * mean[r], 0.f);
        rs[r] = rsqrtf(var + 1e-5f);
    }
    a0 = (a0 - mean) * rs * g0 + b0;
    a1 = (a1 - mean) * rs * g1 + b1;
    a2 = (a2 - mean) * rs * g2 + b2;
    a3 = (a3 - mean) * rs * g3 + b3;
    if (DOGELU) { a0 = gelu4(a0); a1 = gelu4(a1); a2 = gelu4(a2); a3 = gelu4(a3); }
}

template <bool DOGELU>
__device__ __forceinline__ void ln128(float &x0, float &x1, float g0_, float g1_,
                                      float b0_, float b1_) {
    float s = x0 + x1, q = x0 * x0 + x1 * x1;
#pragma unroll
    for (int o = 1; o < 64; o <<= 1) { s += __shfl_xor(s, o, 64); q += __shfl_xor(q, o, 64); }
    float mean = s * (1.f / 128.f);
    float var  = fmaxf(q * (1.f / 128.f) - mean * mean, 0.f);
    float rs   = rsqrtf(var + 1e-5f);
    x0 = (x0 - mean) * rs * g0_ + b0_;
    x1 = (x1 - mean) * rs * g1_ + b1_;
    if (DOGELU) { x0 = geluf(x0); x1 = geluf(x1); }
}

__device__ __forceinline__ void store_c(unsigned short (*xr)[136], int colbase, int L,
                                        v4f a0, v4f a1, v4f a2, v4f a3) {
    const int c = L & 15, g = L >> 4;
#pragma unroll
    for (int r = 0; r < 4; r++) {
        xr[4 * g + r][colbase + c]      = f2bs(a0[r]);
        xr[4 * g + r][colbase + 16 + c] = f2bs(a1[r]);
        xr[4 * g + r][colbase + 32 + c] = f2bs(a2[r]);
        xr[4 * g + r][colbase + 48 + c] = f2bs(a3[r]);
    }
}

__device__ __forceinline__ v8s pack8(v4f lo, v4f hi) {
    v8s r;
    r[0] = (short)f2bs(lo[0]); r[1] = (short)f2bs(lo[1]);
    r[2] = (short)f2bs(lo[2]); r[3] = (short)f2bs(lo[3]);
    r[4] = (short)f2bs(hi[0]); r[5] = (short)f2bs(hi[1]);
    r[6] = (short)f2bs(hi[2]); r[7] = (short)f2bs(hi[3]);
    return r;
}

struct Params {
    const float *node_states, *edge_features;
    const float *ee_w1, *ee_b1, *ee_ln_g, *ee_ln_b, *ee_w2, *ee_b2;
    const float *ts_w1, *ts_b1, *ts_ln_g, *ts_ln_b, *ts_w2, *ts_b2, *ts_w3, *ts_b3;
    const float *mc_w1, *mc_b1, *mc_ln_g, *mc_ln_b, *mc_w2, *mc_b2;
    const float *at_in_w, *at_in_b, *at_out_w, *at_out_b;
    const float *ag_w1, *ag_b1, *ag_ln_g, *ag_ln_b, *ag_w2, *ag_b2;
    const float *gt_w, *gt_b, *nn_ln_g, *nn_ln_b, *mn_ln_g, *mn_ln_b;
    float *ws;
    float *out;
};

// ---- prep: identical to R9/R10 ----
__global__ __launch_bounds__(256) void prep_kernel(Params p) {
    int i = blockIdx.x * 256 + threadIdx.x;
    if (i < F_TOTAL) {
        float v;
        if (i < F_BMC) {
            int o = i - F_BTS;
            float s = p.ts_b1[o];
            for (int e = 0; e < E_; e++) s += p.ee_b2[e] * p.ts_w1[e * M_ + o];
            v = s;
        } else if (i < F_AOP) {
            int o = i - F_BMC;
            float s = p.mc_b1[o];
            for (int e = 0; e < E_; e++) s += p.ee_b2[e] * p.mc_w1[(D_ + e) * M_ + o];
            v = s;
        } else if (i < F_AG1P) {
            int x = i - F_AOP, r = x >> 2, kk = x & 3, k4 = r >> 6, ch = r & 63;
            v = p.at_out_w[(4 * k4 + kk) * M_ + ch];
        } else if (i < F_AG2P) {
            int x = i - F_AG1P, r = x >> 2, kk = x & 3, k4 = r >> 7, ch = r & 127;
            v = p.ag_w1[(4 * k4 + kk) * D_ + ch];
        } else if (i < F_GTP) {
            int x = i - F_AG2P, r = x >> 2, kk = x & 3, k4 = r >> 7, ch = r & 127;
            v = p.ag_w2[(4 * k4 + kk) * D_ + ch];
        } else {
            int x = i - F_GTP, r = x >> 2, kk = x & 3, k4 = r >> 7, ch = r & 127;
            v = p.gt_w[(4 * k4 + kk) * D_ + ch];
        }
        p.ws[i] = v;
        return;
    }
    int hi = i - F_TOTAL;
    if (hi >= H_TOTAL) return;
    unsigned short *wsh = (unsigned short *)(p.ws + F_TOTAL);
    int base, NT;
    const int region =
        (hi < H_WTS) ? 0 : (hi < H_TS2) ? 1 : (hi < H_MC1) ? 2 :
        (hi < H_WMCE) ? 3 : (hi < H_MC2) ? 4 : (hi < H_ATI) ? 5 : 6;
    switch (region) {
        case 0: base = H_EE1;  NT = 4;  break;
        case 1: base = H_WTS;  NT = 4;  break;
        case 2: base = H_TS2;  NT = 2;  break;
        case 3: base = H_MC1;  NT = 4;  break;
        case 4: base = H_WMCE; NT = 4;  break;
        case 5: base = H_MC2;  NT = 4;  break;
        default: base = H_ATI; NT = 12; break;
    }
    int r0 = hi - base;
    int j  = r0 & 7, L = (r0 >> 3) & 63, tk = r0 >> 9;
    int kc = tk / NT, T = tk - kc * NT;
    int c  = L & 15, gg = L >> 4;
    int k  = 32 * kc + 8 * gg + j;
    int n  = 16 * T + c;
    float v = 0.f;
    switch (region) {
        case 0: v = (k < E_) ? p.ee_w1[k * M_ + n] : 0.f; break;
        case 1: { float s = 0.f;
                  for (int e = 0; e < E_; e++) s += p.ee_w2[k * E_ + e] * p.ts_w1[e * M_ + n];
                  v = s; } break;
        case 2: v = p.ts_w2[k * 32 + n]; break;
        case 3: v = p.mc_w1[k * M_ + n]; break;
        case 4: { float s = 0.f;
                  for (int e = 0; e < E_; e++) s += p.ee_w2[k * E_ + e] * p.mc_w1[(D_ + e) * M_ + n];
                  v = s; } break;
        case 5: v = p.mc_w2[k * M_ + n]; break;
        default: v = p.at_in_w[k * 192 + n]; break;
    }
    wsh[hi] = f2bs(v);
}

#define SPL4(NAME, EXPR) v4f NAME; { float _b = (EXPR); NAME = (v4f){_b, _b, _b, _b}; }

// two tasks per wave (A=2i, B=2i+1), stages back-to-back in one barrier-free
// region. LDS: node-phase fp32 staging (xv) OVERLAYS the xp transpose buffer —
// xp is dead after the attention phase, all aliasing is same-wave in-order DS.
// 34,816 B/block -> 4 blocks/CU (was 43,008 -> 3), matching the VGPR=108 4-wave cap.
__global__ __launch_bounds__(256) void petri_kernel(Params p) {
    const int tid = threadIdx.x;
    const int w   = tid >> 6;
    const int L   = tid & 63;
    const int c   = L & 15, g = L >> 4;
    const int taskA = blockIdx.x * 8 + w * 2;
    const int taskB = taskA + 1;
    const int bsA = taskA / N_, tA = taskA - bsA * N_;
    const int bsB = taskB / N_, tB = taskB - bsB * N_;
    const int mrow = (c < N_) ? c : 0;

    __shared__ __align__(16) unsigned short xp[4][2][16][136];
    // node-phase fp32 staging aliases xp (per task: 256 floats = 1024 B < 4352 B)
    float *xvA = (float *)&xp[w][0][0][0];
    float *xvB = (float *)&xp[w][1][0][0];

    const float *ws = p.ws;
    const v8s *wb = (const v8s *)((const unsigned short *)(ws + F_TOTAL));
    const v8s zf = {0, 0, 0, 0, 0, 0, 0, 0};

    // =========== E1 (A,B) ===========
    v8s ahA0, ahA1, ahB0, ahB1;
    {
        v8s aA, aB;
        {
            const float *eA = p.edge_features + (((size_t)bsA * N_ + mrow) * N_ + tA) * E_;
            const float *eB = p.edge_features + (((size_t)bsB * N_ + mrow) * N_ + tB) * E_;
            v2f fa = ((const v2f *)eA)[0], fb = ((const v2f *)eA)[1], fc = ((const v2f *)eA)[2];
            v2f ga_ = ((const v2f *)eB)[0], gb = ((const v2f *)eB)[1], gc = ((const v2f *)eB)[2];
            v8s ta = zf, tb = zf;
            ta[0] = (short)f2bs(fa.x); ta[1] = (short)f2bs(fa.y);
            ta[2] = (short)f2bs(fb.x); ta[3] = (short)f2bs(fb.y);
            ta[4] = (short)f2bs(fc.x); ta[5] = (short)f2bs(fc.y);
            tb[0] = (short)f2bs(ga_.x); tb[1] = (short)f2bs(ga_.y);
            tb[2] = (short)f2bs(gb.x); tb[3] = (short)f2bs(gb.y);
            tb[4] = (short)f2bs(gc.x); tb[5] = (short)f2bs(gc.y);
            aA = (g == 0) ? ta : zf;
            aB = (g == 0) ? tb : zf;
        }
        float b0 = p.ee_b1[c], b1 = p.ee_b1[16 + c], b2 = p.ee_b1[32 + c], b3 = p.ee_b1[48 + c];
        v4f h0A = {b0, b0, b0, b0}, h1A = {b1, b1, b1, b1}, h2A = {b2, b2, b2, b2}, h3A = {b3, b3, b3, b3};
        v4f h0B = h0A, h1B = h1A, h2B = h2A, h3B = h3A;
        {
            v8s W0 = wb[0 * 64 + L], W1 = wb[1 * 64 + L], W2 = wb[2 * 64 + L], W3 = wb[3 * 64 + L];
            h0A = MFMA16(aA, W0, h0A); h0B = MFMA16(aB, W0, h0B);
            h1A = MFMA16(aA, W1, h1A); h1B = MFMA16(aB, W1, h1B);
            h2A = MFMA16(aA, W2, h2A); h2B = MFMA16(aB, W2, h2B);
            h3A = MFMA16(aA, W3, h3A); h3B = MFMA16(aB, W3, h3B);
        }
        float lg0 = p.ee_ln_g[c], lg1 = p.ee_ln_g[16 + c], lg2 = p.ee_ln_g[32 + c], lg3 = p.ee_ln_g[48 + c];
        float lb0 = p.ee_ln_b[c], lb1 = p.ee_ln_b[16 + c], lb2 = p.ee_ln_b[32 + c], lb3 = p.ee_ln_b[48 + c];
        ln_c64<true>(h0A, h1A, h2A, h3A, lg0, lg1, lg2, lg3, lb0, lb1, lb2, lb3);
        ln_c64<true>(h0B, h1B, h2B, h3B, lg0, lg1, lg2, lg3, lb0, lb1, lb2, lb3);
        store_c(xp[w][0], 64, L, h0A, h1A, h2A, h3A);
        store_c(xp[w][1], 64, L, h0B, h1B, h2B, h3B);
        LDS_ORDER();
        ahA0 = *(const v8s *)&xp[w][0][c][64 + 8 * g];
        ahA1 = *(const v8s *)&xp[w][0][c][96 + 8 * g];
        ahB0 = *(const v8s *)&xp[w][1][c][64 + 8 * g];
        ahB1 = *(const v8s *)&xp[w][1][c][96 + 8 * g];
    }

    // =========== TS1 + TS2/3 (A,B) ===========
    v4f tsvA, tsvB;
    {
        float b0 = ws[F_BTS + c], b1 = ws[F_BTS + 16 + c], b2 = ws[F_BTS + 32 + c], b3 = ws[F_BTS + 48 + c];
        v4f t0A = {b0, b0, b0, b0}, t1A = {b1, b1, b1, b1}, t2A = {b2, b2, b2, b2}, t3A = {b3, b3, b3, b3};
        v4f t0B = t0A, t1B = t1A, t2B = t2A, t3B = t3A;
        {
            v8s W;
            W = wb[256 + 0 * 64 + L]; t0A = MFMA16(ahA0, W, t0A); t0B = MFMA16(ahB0, W, t0B);
            W = wb[256 + 4 * 64 + L]; t0A = MFMA16(ahA1, W, t0A); t0B = MFMA16(ahB1, W, t0B);
            W = wb[256 + 1 * 64 + L]; t1A = MFMA16(ahA0, W, t1A); t1B = MFMA16(ahB0, W, t1B);
            W = wb[256 + 5 * 64 + L]; t1A = MFMA16(ahA1, W, t1A); t1B = MFMA16(ahB1, W, t1B);
            W = wb[256 + 2 * 64 + L]; t2A = MFMA16(ahA0, W, t2A); t2B = MFMA16(ahB0, W, t2B);
            W = wb[256 + 6 * 64 + L]; t2A = MFMA16(ahA1, W, t2A); t2B = MFMA16(ahB1, W, t2B);
            W = wb[256 + 3 * 64 + L]; t3A = MFMA16(ahA0, W, t3A); t3B = MFMA16(ahB0, W, t3B);
            W = wb[256 + 7 * 64 + L]; t3A = MFMA16(ahA1, W, t3A); t3B = MFMA16(ahB1, W, t3B);
        }
        float lg0 = p.ts_ln_g[c], lg1 = p.ts_ln_g[16 + c], lg2 = p.ts_ln_g[32 + c], lg3 = p.ts_ln_g[48 + c];
        float lb0 = p.ts_ln_b[c], lb1 = p.ts_ln_b[16 + c], lb2 = p.ts_ln_b[32 + c], lb3 = p.ts_ln_b[48 + c];
        ln_c64<true>(t0A, t1A, t2A, t3A, lg0, lg1, lg2, lg3, lb0, lb1, lb2, lb3);
        ln_c64<true>(t0B, t1B, t2B, t3B, lg0, lg1, lg2, lg3, lb0, lb1, lb2, lb3);
        store_c(xp[w][0], 0, L, t0A, t1A, t2A, t3A);
        store_c(xp[w][1], 0, L, t0B, t1B, t2B, t3B);
        LDS_ORDER();
        v8s atA0 = *(const v8s *)&xp[w][0][c][0 + 8 * g];
        v8s atA1 = *(const v8s *)&xp[w][0][c][32 + 8 * g];
        v8s atB0 = *(const v8s *)&xp[w][1][c][0 + 8 * g];
        v8s atB1 = *(const v8s *)&xp[w][1][c][32 + 8 * g];
        float u0b = p.ts_b2[c], u1b = p.ts_b2[16 + c];
        v4f u0A = {u0b, u0b, u0b, u0b}, u1A = {u1b, u1b, u1b, u1b};
        v4f u0B = u0A, u1B = u1A;
        {
            v8s W;
            W = wb[768 + 0 * 64 + L]; u0A = MFMA16(atA0, W, u0A); u0B = MFMA16(atB0, W, u0B);
            W = wb[768 + 2 * 64 + L]; u0A = MFMA16(atA1, W, u0A); u0B = MFMA16(atB1, W, u0B);
            W = wb[768 + 1 * 64 + L]; u1A = MFMA16(atA0, W, u1A); u1B = MFMA16(atB0, W, u1B);
            W = wb[768 + 3 * 64 + L]; u1A = MFMA16(atA1, W, u1A); u1B = MFMA16(atB1, W, u1B);
        }
        float w3a = p.ts_w3[c], w3b = p.ts_w3[16 + c], b3v = p.ts_b3[0];
        v4f dA = gelu4(u0A) * w3a + gelu4(u1A) * w3b;
        v4f dB = gelu4(u0B) * w3a + gelu4(u1B) * w3b;
#pragma unroll
        for (int o = 1; o < 16; o <<= 1)
#pragma unroll
            for (int r = 0; r < 4; r++) {
                dA[r] += __shfl_xor(dA[r], o, 64);
                dB[r] += __shfl_xor(dB[r], o, 64);
            }
#pragma unroll
        for (int r = 0; r < 4; r++) {
            tsvA[r] = sigm(dA[r] + b3v);
            tsvB[r] = sigm(dB[r] + b3v);
        }
    }

    // =========== MC1 (A,B) ===========
    v8s amA0, amA1, amB0, amB1;
    {
        float b0 = ws[F_BMC + c], b1 = ws[F_BMC + 16 + c], b2 = ws[F_BMC + 32 + c], b3 = ws[F_BMC + 48 + c];
        v4f m0A = {b0, b0, b0, b0}, m1A = {b1, b1, b1, b1}, m2A = {b2, b2, b2, b2}, m3A = {b3, b3, b3, b3};
        v4f m0B = m0A, m1B = m1A, m2B = m2A, m3B = m3A;
        const float *nsrA = p.node_states + ((size_t)bsA * N_ + mrow) * D_;
        const float *nsrB = p.node_states + ((size_t)bsB * N_ + mrow) * D_;
#pragma unroll
        for (int kc = 0; kc < 4; kc++) {
            v8s anA = pack8(*(const v4f *)(nsrA + 32 * kc + 8 * g),
                            *(const v4f *)(nsrA + 32 * kc + 8 * g + 4));
            v8s anB = pack8(*(const v4f *)(nsrB + 32 * kc + 8 * g),
                            *(const v4f *)(nsrB + 32 * kc + 8 * g + 4));
            v8s W;
            W = wb[1024 + (kc * 4 + 0) * 64 + L]; m0A = MFMA16(anA, W, m0A); m0B = MFMA16(anB, W, m0B);
            W = wb[1024 + (kc * 4 + 1) * 64 + L]; m1A = MFMA16(anA, W, m1A); m1B = MFMA16(anB, W, m1B);
            W = wb[1024 + (kc * 4 + 2) * 64 + L]; m2A = MFMA16(anA, W, m2A); m2B = MFMA16(anB, W, m2B);
            W = wb[1024 + (kc * 4 + 3) * 64 + L]; m3A = MFMA16(anA, W, m3A); m3B = MFMA16(anB, W, m3B);
        }
        {
            v8s W;
            W = wb[2048 + 0 * 64 + L]; m0A = MFMA16(ahA0, W, m0A); m0B = MFMA16(ahB0, W, m0B);
            W = wb[2048 + 4 * 64 + L]; m0A = MFMA16(ahA1, W, m0A); m0B = MFMA16(ahB1, W, m0B);
            W = wb[2048 + 1 * 64 + L]; m1A = MFMA16(ahA0, W, m1A); m1B = MFMA16(ahB0, W, m1B);
            W = wb[2048 + 5 * 64 + L]; m1A = MFMA16(ahA1, W, m1A); m1B = MFMA16(ahB1, W, m1B);
            W = wb[2048 + 2 * 64 + L]; m2A = MFMA16(ahA0, W, m2A); m2B = MFMA16(ahB0, W, m2B);
            W = wb[2048 + 6 * 64 + L]; m2A = MFMA16(ahA1, W, m2A); m2B = MFMA16(ahB1, W, m2B);
            W = wb[2048 + 3 * 64 + L]; m3A = MFMA16(ahA0, W, m3A); m3B = MFMA16(ahB0, W, m3B);
            W = wb[2048 + 7 * 64 + L]; m3A = MFMA16(ahA1, W, m3A); m3B = MFMA16(ahB1, W, m3B);
        }
        float lg0 = p.mc_ln_g[c], lg1 = p.mc_ln_g[16 + c], lg2 = p.mc_ln_g[32 + c], lg3 = p.mc_ln_g[48 + c];
        float lb0 = p.mc_ln_b[c], lb1 = p.mc_ln_b[16 + c], lb2 = p.mc_ln_b[32 + c], lb3 = p.mc_ln_b[48 + c];
        ln_c64<true>(m0A, m1A, m2A, m3A, lg0, lg1, lg2, lg3, lb0, lb1, lb2, lb3);
        ln_c64<true>(m0B, m1B, m2B, m3B, lg0, lg1, lg2, lg3, lb0, lb1, lb2, lb3);
        store_c(xp[w][0], 0, L, m0A, m1A, m2A, m3A);
        store_c(xp[w][1], 0, L, m0B, m1B, m2B, m3B);
        LDS_ORDER();
        amA0 = *(const v8s *)&xp[w][0][c][0 + 8 * g];
        amA1 = *(const v8s *)&xp[w][0][c][32 + 8 * g];
        amB0 = *(const v8s *)&xp[w][1][c][0 + 8 * g];
        amB1 = *(const v8s *)&xp[w][1][c][32 + 8 * g];
    }

    // =========== MC2 (A,B) ===========
    v8s awA0, awA1, awB0, awB1;
    {
        float b0 = p.mc_b2[c], b1 = p.mc_b2[16 + c], b2 = p.mc_b2[32 + c], b3 = p.mc_b2[48 + c];
        v4f x0A = {b0, b0, b0, b0}, x1A = {b1, b1, b1, b1}, x2A = {b2, b2, b2, b2}, x3A = {b3, b3, b3, b3};
        v4f x0B = x0A, x1B = x1A, x2B = x2A, x3B = x3A;
        {
            v8s W;
            W = wb[2560 + 0 * 64 + L]; x0A = MFMA16(amA0, W, x0A); x0B = MFMA16(amB0, W, x0B);
            W = wb[2560 + 4 * 64 + L]; x0A = MFMA16(amA1, W, x0A); x0B = MFMA16(amB1, W, x0B);
            W = wb[2560 + 1 * 64 + L]; x1A = MFMA16(amA0, W, x1A); x1B = MFMA16(amB0, W, x1B);
            W = wb[2560 + 5 * 64 + L]; x1A = MFMA16(amA1, W, x1A); x1B = MFMA16(amB1, W, x1B);
            W = wb[2560 + 2 * 64 + L]; x2A = MFMA16(amA0, W, x2A); x2B = MFMA16(amB0, W, x2B);
            W = wb[2560 + 6 * 64 + L]; x2A = MFMA16(amA1, W, x2A); x2B = MFMA16(amB1, W, x2B);
            W = wb[2560 + 3 * 64 + L]; x3A = MFMA16(amA0, W, x3A); x3B = MFMA16(amB0, W, x3B);
            W = wb[2560 + 7 * 64 + L]; x3A = MFMA16(amA1, W, x3A); x3B = MFMA16(amB1, W, x3B);
        }
        x0A *= tsvA; x1A *= tsvA; x2A *= tsvA; x3A *= tsvA;
        x0B *= tsvB; x1B *= tsvB; x2B *= tsvB; x3B *= tsvB;
        float lg0 = p.mn_ln_g[c], lg1 = p.mn_ln_g[16 + c], lg2 = p.mn_ln_g[32 + c], lg3 = p.mn_ln_g[48 + c];
        float lb0 = p.mn_ln_b[c], lb1 = p.mn_ln_b[16 + c], lb2 = p.mn_ln_b[32 + c], lb3 = p.mn_ln_b[48 + c];
        ln_c64<false>(x0A, x1A, x2A, x3A, lg0, lg1, lg2, lg3, lb0, lb1, lb2, lb3);
        ln_c64<false>(x0B, x1B, x2B, x3B, lg0, lg1, lg2, lg3, lb0, lb1, lb2, lb3);
        store_c(xp[w][0], 0, L, x0A, x1A, x2A, x3A);
        store_c(xp[w][1], 0, L, x0B, x1B, x2B, x3B);
        LDS_ORDER();
        awA0 = *(const v8s *)&xp[w][0][c][0 + 8 * g];
        awA1 = *(const v8s *)&xp[w][0][c][32 + 8 * g];
        awB0 = *(const v8s *)&xp[w][1][c][0 + 8 * g];
        awB1 = *(const v8s *)&xp[w][1][c][32 + 8 * g];
    }

    // =========== AT: Q,K stored per-tile; V kept in regs ===========
    v4f vtA0, vtA1, vtA2, vtA3, vtB0, vtB1, vtB2, vtB3;
    {
#define AT_QK(T, DSTC)                                                          \
        { float _b = p.at_in_b[16 * (T) + c];                                    \
          v8s W0 = wb[3072 + (T) * 64 + L], W1 = wb[3072 + (12 + (T)) * 64 + L]; \
          v4f aA = {_b, _b, _b, _b}, aB = aA;                                    \
          aA = MFMA16(awA0, W0, aA); aA = MFMA16(awA1, W1, aA);                  \
          aB = MFMA16(awB0, W0, aB); aB = MFMA16(awB1, W1, aB);                  \
          _Pragma("unroll")                                                      \
          for (int r = 0; r < 4; r++) {                                          \
              xp[w][0][4 * g + r][(DSTC) + c] = f2bs(aA[r]);                     \
              xp[w][1][4 * g + r][(DSTC) + c] = f2bs(aB[r]);                     \
          } }
        AT_QK(0, 0)  AT_QK(1, 16)  AT_QK(2, 32)  AT_QK(3, 48)
        AT_QK(4, 64) AT_QK(5, 80)  AT_QK(6, 96)  AT_QK(7, 112)
#undef AT_QK
#define AT_V(T, VA, VB)                                                          \
        { float _b = p.at_in_b[16 * (T) + c];                                    \
          v8s W0 = wb[3072 + (T) * 64 + L], W1 = wb[3072 + (12 + (T)) * 64 + L]; \
          VA = (v4f){_b, _b, _b, _b}; VB = VA;                                   \
          VA = MFMA16(awA0, W0, VA); VA = MFMA16(awA1, W1, VA);                  \
          VB = MFMA16(awB0, W0, VB); VB = MFMA16(awB1, W1, VB); }
        AT_V(8, vtA0, vtB0) AT_V(9, vtA1, vtB1) AT_V(10, vtA2, vtB2) AT_V(11, vtA3, vtB3)
#undef AT_V
        LDS_ORDER();
    }

    // =========== attention (A,B) ===========
    float agA0, agA1, agA2, agA3, agB0, agB1, agB2, agB3;
#define ATTN(TI, VT0, VT1, VT2, VT3, O0, O1, O2, O3)                              \
    {                                                                             \
        const v4f z4 = {0.f, 0.f, 0.f, 0.f};                                      \
        v4f s0, s1, s2, s3;                                                       \
        {                                                                         \
            v8s aq, bk;                                                           \
            aq = (g < 2) ? *(const v8s *)&xp[w][TI][c][0 + 8 * g] : zf;           \
            bk = (g < 2) ? *(const v8s *)&xp[w][TI][c][64 + 0 + 8 * g] : zf;      \
            s0 = MFMA16(aq, bk, z4);                                              \
            aq = (g < 2) ? *(const v8s *)&xp[w][TI][c][16 + 8 * g] : zf;          \
            bk = (g < 2) ? *(const v8s *)&xp[w][TI][c][64 + 16 + 8 * g] : zf;     \
            s1 = MFMA16(aq, bk, z4);                                              \
            aq = (g < 2) ? *(const v8s *)&xp[w][TI][c][32 + 8 * g] : zf;          \
            bk = (g < 2) ? *(const v8s *)&xp[w][TI][c][64 + 32 + 8 * g] : zf;     \
            s2 = MFMA16(aq, bk, z4);                                              \
            aq = (g < 2) ? *(const v8s *)&xp[w][TI][c][48 + 8 * g] : zf;          \
            bk = (g < 2) ? *(const v8s *)&xp[w][TI][c][64 + 48 + 8 * g] : zf;     \
            s3 = MFMA16(aq, bk, z4);                                              \
        }                                                                         \
        if (c >= N_) {                                                            \
            v4f neg = {-1e30f, -1e30f, -1e30f, -1e30f};                           \
            s0 = neg; s1 = neg; s2 = neg; s3 = neg;                               \
        }                                                                         \
        v4f m0 = s0, m1 = s1, m2 = s2, m3 = s3;                                   \
        _Pragma("unroll")                                                         \
        for (int o = 1; o < 16; o <<= 1)                                          \
            _Pragma("unroll")                                                     \
            for (int r = 0; r < 4; r++) {                                         \
                m0[r] = fmaxf(m0[r], __shfl_xor(m0[r], o, 64));                   \
                m1[r] = fmaxf(m1[r], __shfl_xor(m1[r], o, 64));                   \
                m2[r] = fmaxf(m2[r], __shfl_xor(m2[r], o, 64));                   \
                m3[r] = fmaxf(m3[r], __shfl_xor(m3[r], o, 64));                   \
            }                                                                     \
        v4f e0, e1, e2, e3;                                                       \
        _Pragma("unroll")                                                         \
        for (int r = 0; r < 4; r++) {                                             \
            e0[r] = __expf((s0[r] - m0[r]) * 0.25f);                              \
            e1[r] = __expf((s1[r] - m1[r]) * 0.25f);                              \
            e2[r] = __expf((s2[r] - m2[r]) * 0.25f);                              \
            e3[r] = __expf((s3[r] - m3[r]) * 0.25f);                              \
        }                                                                         \
        v4f z0 = e0, z1 = e1, z2 = e2, z3 = e3;                                   \
        _Pragma("unroll")                                                         \
        for (int o = 1; o < 16; o <<= 1)                                          \
            _Pragma("unroll")                                                     \
            for (int r = 0; r < 4; r++) {                                         \
                z0[r] += __shfl_xor(z0[r], o, 64);                                \
                z1[r] += __shfl_xor(z1[r], o, 64);                                \
                z2[r] += __shfl_xor(z2[r], o, 64);                                \
                z3[r] += __shfl_xor(z3[r], o, 64);                                \
            }                                                                     \
        _Pragma("unroll")                                                         \
        for (int r = 0; r < 4; r++) {                                             \
            e0[r] *= __builtin_amdgcn_rcpf(z0[r]);                                \
            e1[r] *= __builtin_amdgcn_rcpf(z1[r]);                                \
            e2[r] *= __builtin_amdgcn_rcpf(z2[r]);                                \
            e3[r] *= __builtin_amdgcn_rcpf(z3[r]);                                \
        }                                                                         \
        int row0 = 4 * g;                                                         \
        float cs0 = e0[0], cs1 = e1[0], cs2 = e2[0], cs3 = e3[0];                 \
        _Pragma("unroll")                                                         \
        for (int r = 1; r < 4; r++) {                                             \
            bool ok = (row0 + r) < N_;                                            \
            cs0 += ok ? e0[r] : 0.f; cs1 += ok ? e1[r] : 0.f;                     \
            cs2 += ok ? e2[r] : 0.f; cs3 += ok ? e3[r] : 0.f;                     \
        }                                                                         \
        cs0 += __shfl_xor(cs0, 16, 64); cs0 += __shfl_xor(cs0, 32, 64);           \
        cs1 += __shfl_xor(cs1, 16, 64); cs1 += __shfl_xor(cs1, 32, 64);           \
        cs2 += __shfl_xor(cs2, 16, 64); cs2 += __shfl_xor(cs2, 32, 64);           \
        cs3 += __shfl_xor(cs3, 16, 64); cs3 += __shfl_xor(cs3, 32, 64);           \
        int pbase = (((L & 48) + ((L & 48) >> 2)) << 2);                          \
        O0 = 0.f; O1 = 0.f; O2 = 0.f; O3 = 0.f;                                   \
        _Pragma("unroll")                                                         \
        for (int r = 0; r < 4; r++) {                                             \
            int pa = pbase + 4 * r;                                               \
            float c0 = __int_as_float(__builtin_amdgcn_ds_bpermute(pa, __float_as_int(cs0))); \
            float c1 = __int_as_float(__builtin_amdgcn_ds_bpermute(pa, __float_as_int(cs1))); \
            float c2 = __int_as_float(__builtin_amdgcn_ds_bpermute(pa, __float_as_int(cs2))); \
            float c3 = __int_as_float(__builtin_amdgcn_ds_bpermute(pa, __float_as_int(cs3))); \
            O0 += c0 * VT0[r]; O1 += c1 * VT1[r];                                 \
            O2 += c2 * VT2[r]; O3 += c3 * VT3[r];                                 \
        }                                                                         \
        O0 += __shfl_xor(O0, 16, 64); O0 += __shfl_xor(O0, 32, 64);               \
        O1 += __shfl_xor(O1, 16, 64); O1 += __shfl_xor(O1, 32, 64);               \
        O2 += __shfl_xor(O2, 16, 64); O2 += __shfl_xor(O2, 32, 64);               \
        O3 += __shfl_xor(O3, 16, 64); O3 += __shfl_xor(O3, 32, 64);               \
        const float inv13 = 1.0f / 13.0f;                                         \
        O0 *= inv13; O1 *= inv13; O2 *= inv13; O3 *= inv13;                       \
    }
    ATTN(0, vtA0, vtA1, vtA2, vtA3, agA0, agA1, agA2, agA3)
    ATTN(1, vtB0, vtB1, vtB2, vtB3, agB0, agB1, agB2, agB3)
#undef ATTN
    LDS_ORDER();   // xp dead from here; xvA/xvB (aliased) become live

    // =========== node phase (A,B joint, shared weight loads) ===========
    if (g == 0) {
        xvA[c] = agA0; xvA[16 + c] = agA1; xvA[32 + c] = agA2; xvA[48 + c] = agA3;
        xvB[c] = agB0; xvB[16 + c] = agB1; xvB[32 + c] = agB2; xvB[48 + c] = agB3;
    }
    LDS_ORDER();
    {   // at_out
        const v4f *AO = (const v4f *)(ws + F_AOP);
        v2f spA = mkpair(p.at_out_b[L], 0.f), spB = spA;
#pragma unroll 4
        for (int k4 = 0; k4 < 16; k4++) {
            v4f wv = AO[k4 * 64 + L];
            v4f xA = *(const v4f *)&xvA[4 * k4];
            v4f xB = *(const v4f *)&xvB[4 * k4];
            spA = PKFMA(LO2(xA), LO2(wv), PKFMA(HI2(xA), HI2(wv), spA));
            spB = PKFMA(LO2(xB), LO2(wv), PKFMA(HI2(xB), HI2(wv), spB));
        }
        xvA[64 + L] = spA.x + spA.y;
        xvB[64 + L] = spB.x + spB.y;
    }
    LDS_ORDER();
    {   // ag1 -> LN -> gelu
        const v4f *AG = (const v4f *)(ws + F_AG1P);
        float bb0 = p.ag_b1[L], bb1 = p.ag_b1[L + 64];
        v2f pA0 = mkpair(bb0, 0.f), pA1 = mkpair(bb1, 0.f);
        v2f pB0 = pA0, pB1 = pA1;
#pragma unroll 4
        for (int k4 = 0; k4 < 16; k4++) {
            v4f w0 = AG[k4 * 128 + L], w1 = AG[k4 * 128 + 64 + L];
            v4f xA = *(const v4f *)&xvA[64 + 4 * k4];
            v4f xB = *(const v4f *)&xvB[64 + 4 * k4];
            pA0 = PKFMA(LO2(xA), LO2(w0), PKFMA(HI2(xA), HI2(w0), pA0));
            pA1 = PKFMA(LO2(xA), LO2(w1), PKFMA(HI2(xA), HI2(w1), pA1));
            pB0 = PKFMA(LO2(xB), LO2(w0), PKFMA(HI2(xB), HI2(w0), pB0));
            pB1 = PKFMA(LO2(xB), LO2(w1), PKFMA(HI2(xB), HI2(w1), pB1));
        }
        float aA0 = pA0.x + pA0.y, aA1 = pA1.x + pA1.y;
        float aB0 = pB0.x + pB0.y, aB1 = pB1.x + pB1.y;
        float lg0 = p.ag_ln_g[L], lg1 = p.ag_ln_g[L + 64];
        float lb0 = p.ag_ln_b[L], lb1 = p.ag_ln_b[L + 64];
        ln128<true>(aA0, aA1, lg0, lg1, lb0, lb1);
        ln128<true>(aB0, aB1, lg0, lg1, lb0, lb1);
        xvA[128 + L] = aA0; xvA[192 + L] = aA1;
        xvB[128 + L] = aB0; xvB[192 + L] = aB1;
    }
    LDS_ORDER();
    float nivA0, nivA1, nivB0, nivB1;
    {   // ag2
        const v4f *AG = (const v4f *)(ws + F_AG2P);
        float bb0 = p.ag_b2[L], bb1 = p.ag_b2[L + 64];
        v2f pA0 = mkpair(bb0, 0.f), pA1 = mkpair(bb1, 0.f);
        v2f pB0 = pA0, pB1 = pA1;
#pragma unroll 8
        for (int k4 = 0; k4 < 32; k4++) {
            v4f w0 = AG[k4 * 128 + L], w1 = AG[k4 * 128 + 64 + L];
            v4f xA = *(const v4f *)&xvA[128 + 4 * k4];
            v4f xB = *(const v4f *)&xvB[128 + 4 * k4];
            pA0 = PKFMA(LO2(xA), LO2(w0), PKFMA(HI2(xA), HI2(w0), pA0));
            pA1 = PKFMA(LO2(xA), LO2(w1), PKFMA(HI2(xA), HI2(w1), pA1));
            pB0 = PKFMA(LO2(xB), LO2(w0), PKFMA(HI2(xB), HI2(w0), pB0));
            pB1 = PKFMA(LO2(xB), LO2(w1), PKFMA(HI2(xB), HI2(w1), pB1));
        }
        nivA0 = pA0.x + pA0.y; nivA1 = pA1.x + pA1.y;
        nivB0 = pB0.x + pB0.y; nivB1 = pB1.x + pB1.y;
    }
    // stage gate input [ns_t | nil] per task
    const float *nstA = p.node_states + ((size_t)bsA * N_ + tA) * D_;
    const float *nstB = p.node_states + ((size_t)bsB * N_ + tB) * D_;
    float nA0 = nstA[L], nA1 = nstA[L + 64];
    float nB0 = nstB[L], nB1 = nstB[L + 64];
    xvA[L] = nA0; xvA[64 + L] = nA1;
    xvA[128 + L] = nivA0; xvA[192 + L] = nivA1;
    xvB[L] = nB0; xvB[64 + L] = nB1;
    xvB[128 + L] = nivB0; xvB[192 + L] = nivB1;
    LDS_ORDER();
    float updA0, updA1, updB0, updB1;
    {   // gate GEMV K=256
        const v4f *GT = (const v4f *)(ws + F_GTP);
        float bb0 = p.gt_b[L], bb1 = p.gt_b[L + 64];
        v2f pA0 = mkpair(bb0, 0.f), pA1 = mkpair(bb1, 0.f);
        v2f pB0 = pA0, pB1 = pA1;
#pragma unroll 8
        for (int k4 = 0; k4 < 64; k4++) {
            v4f w0 = GT[k4 * 128 + L], w1 = GT[k4 * 128 + 64 + L];
            v4f xA = *(const v4f *)&xvA[4 * k4];
            v4f xB = *(const v4f *)&xvB[4 * k4];
            pA0 = PKFMA(LO2(xA), LO2(w0), PKFMA(HI2(xA), HI2(w0), pA0));
            pA1 = PKFMA(LO2(xA), LO2(w1), PKFMA(HI2(xA), HI2(w1), pA1));
            pB0 = PKFMA(LO2(xB), LO2(w0), PKFMA(HI2(xB), HI2(w0), pB0));
            pB1 = PKFMA(LO2(xB), LO2(w1), PKFMA(HI2(xB), HI2(w1), pB1));
        }
        float gA0 = sigm(pA0.x + pA0.y), gA1 = sigm(pA1.x + pA1.y);
        float gB0 = sigm(pB0.x + pB0.y), gB1 = sigm(pB1.x + pB1.y);
        updA0 = gA0 * nivA0 + (1.f - gA0) * nA0;
        updA1 = gA1 * nivA1 + (1.f - gA1) * nA1;
        updB0 = gB0 * nivB0 + (1.f - gB0) * nB0;
        updB1 = gB1 * nivB1 + (1.f - gB1) * nB1;
    }
    {
        float lg0 = p.nn_ln_g[L], lg1 = p.nn_ln_g[L + 64];
        float lb0 = p.nn_ln_b[L], lb1 = p.nn_ln_b[L + 64];
        ln128<false>(updA0, updA1, lg0, lg1, lb0, lb1);
        ln128<false>(updB0, updB1, lg0, lg1, lb0, lb1);
        float *opA = p.out + ((size_t)bsA * N_ + tA) * D_;
        float *opB = p.out + ((size_t)bsB * N_ + tB) * D_;
        opA[L] = updA0; opA[L + 64] = updA1;
        opB[L] = updB0; opB[L + 64] = updB1;
    }
}

extern "C" void kernel_launch(void* const* d_in, const int* in_sizes, int n_in,
                              void* d_out, int out_size, void* d_ws, size_t ws_size,
                              hipStream_t stream) {
    Params p;
    p.node_states   = (const float*)d_in[0];
    p.edge_features = (const float*)d_in[1];
    p.ee_w1   = (const float*)d_in[2];
    p.ee_b1   = (const float*)d_in[3];
    p.ee_ln_g = (const float*)d_in[4];
    p.ee_ln_b = (const float*)d_in[5];
    p.ee_w2   = (const float*)d_in[6];
    p.ee_b2   = (const float*)d_in[7];
    p.ts_w1   = (const float*)d_in[8];
    p.ts_b1   = (const float*)d_in[9];
    p.ts_ln_g = (const float*)d_in[10];
    p.ts_ln_b = (const float*)d_in[11];
    p.ts_w2   = (const float*)d_in[12];
    p.ts_b2   = (const float*)d_in[13];
    p.ts_w3   = (const float*)d_in[14];
    p.ts_b3   = (const float*)d_in[15];
    p.mc_w1   = (const float*)d_in[16];
    p.mc_b1   = (const float*)d_in[17];
    p.mc_ln_g = (const float*)d_in[18];
    p.mc_ln_b = (const float*)d_in[19];
    p.mc_w2   = (const float*)d_in[20];
    p.mc_b2   = (const float*)d_in[21];
    p.at_in_w  = (const float*)d_in[22];
    p.at_in_b  = (const float*)d_in[23];
    p.at_out_w = (const float*)d_in[24];
    p.at_out_b = (const float*)d_in[25];
    p.ag_w1   = (const float*)d_in[26];
    p.ag_b1   = (const float*)d_in[27];
    p.ag_ln_g = (const float*)d_in[28];
    p.ag_ln_b = (const float*)d_in[29];
    p.ag_w2   = (const float*)d_in[30];
    p.ag_b2   = (const float*)d_in[31];
    p.gt_w    = (const float*)d_in[32];
    p.gt_b    = (const float*)d_in[33];
    p.nn_ln_g = (const float*)d_in[34];
    p.nn_ln_b = (const float*)d_in[35];
    p.mn_ln_g = (const float*)d_in[36];
    p.mn_ln_b = (const float*)d_in[37];
    p.ws      = (float*)d_ws;
    p.out     = (float*)d_out;

    const int prep_threads = F_TOTAL + H_TOTAL;
    hipLaunchKernelGGL(prep_kernel, dim3((prep_threads + 255) / 256), dim3(256), 0, stream, p);
    hipLaunchKernelGGL(petri_kernel, dim3((B_ * S_ * N_) / 8), dim3(256), 0, stream, p);
}